// Round 12
// baseline (439.208 us; speedup 1.0000x reference)
//
#include <hip/hip_runtime.h>

typedef __attribute__((ext_vector_type(8))) short short8;
typedef __attribute__((ext_vector_type(4))) float f32x4;

#define DEV static __device__ __forceinline__
#define QSCALE 0.022097086912079608f

DEV float bfs2f(short s) {
    union { unsigned int u; float f; } c;
    c.u = ((unsigned int)(unsigned short)s) << 16;
    return c.f;
}
DEV short f2bfs(float f) {
    union { float f; unsigned int u; } c;
    c.f = f;
    unsigned int u = c.u;
    return (short)((u + 0x7fffu + ((u >> 16) & 1u)) >> 16);  // RNE
}
DEV int imin(int a, int b) { return a < b ? a : b; }
DEV float sigm(float x) { return 1.f / (1.f + expf(-x)); }

// ---------------------------------------------------------------------------
// Prep 1: f32->bf16 converts (Wq|Wk|Wv|gWih|gWhh) + LN of inputs.
// Segments: Wq 4194304 | Wk 524288 | Wv 524288 | gWih 786432 | gWhh 786432
// blocks [0,26624): converts; [26624,28672): ln_in rows.
// ---------------------------------------------------------------------------
__global__ __launch_bounds__(256) void cvt_ln_k(
    const float* __restrict__ Wq, const float* __restrict__ Wk, const float* __restrict__ Wv,
    const float* __restrict__ gih, const float* __restrict__ ghh,
    short* __restrict__ dWq, short* __restrict__ dWk, short* __restrict__ dWv,
    short* __restrict__ dgih, short* __restrict__ dghh,
    const float* __restrict__ inputs, const float* __restrict__ nig,
    const float* __restrict__ nib, short* __restrict__ xbf)
{
    if (blockIdx.x >= 26624) {
        int row  = (blockIdx.x - 26624) * 4 + (threadIdx.x >> 6);
        int lane = threadIdx.x & 63;
        long off = (long)row * 256 + lane * 4;
        f32x4 v4 = *(const f32x4*)(inputs + off);
        float v[4] = {v4[0], v4[1], v4[2], v4[3]};
        float s = v[0] + v[1] + v[2] + v[3];
        #pragma unroll
        for (int d = 1; d < 64; d <<= 1) s += __shfl_xor(s, d);
        float mean = s * (1.f / 256.f);
        float sq = 0.f;
        #pragma unroll
        for (int k = 0; k < 4; k++) { float dd = v[k] - mean; sq += dd * dd; }
        #pragma unroll
        for (int d = 1; d < 64; d <<= 1) sq += __shfl_xor(sq, d);
        float inv = rsqrtf(sq * (1.f / 256.f) + 1e-5f);
        short* op = xbf + off;
        #pragma unroll
        for (int k = 0; k < 4; k++)
            op[k] = f2bfs((v[k] - mean) * inv * nig[lane * 4 + k] + nib[lane * 4 + k]);
        return;
    }
    long i = (long)blockIdx.x * 256 + threadIdx.x;
    const float* s; short* d; long o;
    if      (i < 4194304) { s = Wq;  d = dWq;  o = i; }
    else if (i < 4718592) { s = Wk;  d = dWk;  o = i - 4194304; }
    else if (i < 5242880) { s = Wv;  d = dWv;  o = i - 4718592; }
    else if (i < 6029312) { s = gih; d = dgih; o = i - 5242880; }
    else                  { s = ghh; d = dghh; o = i - 6029312; }
    d[o] = f2bfs(s[o]);
}

// ---------------------------------------------------------------------------
// Prep 2: weight transposes + c1/b1g folded biases (verified r8).
// ---------------------------------------------------------------------------
__global__ __launch_bounds__(256) void transpose_b1c1_k(
    const float* __restrict__ mW1, const float* __restrict__ mW2,
    const float* __restrict__ cW1, const float* __restrict__ cW2,
    const float* __restrict__ cW3, const float* __restrict__ cW4,
    short* __restrict__ mW1T, short* __restrict__ mW2T,
    short* __restrict__ cW1T, short* __restrict__ cW2T,
    short* __restrict__ cW3T, short* __restrict__ cW4T,
    const float* __restrict__ bq, const float* __restrict__ Wk,
    const float* __restrict__ bv, const float* __restrict__ gWih,
    float* __restrict__ c1, float* __restrict__ b1g)
{
    int id = blockIdx.x, tid = threadIdx.x;
    if (id >= 1152) {
        int bid = id - 1152;
        __shared__ float red[4];
        if (bid < 256) {
            const float* row = Wk + (long)bid * 2048;
            float acc = 0.f;
            for (int d = tid; d < 2048; d += 256) acc += bq[d] * row[d];
            #pragma unroll
            for (int d = 1; d < 64; d <<= 1) acc += __shfl_xor(acc, d);
            int w = tid >> 6;
            if ((tid & 63) == 0) red[w] = acc;
            __syncthreads();
            if (tid == 0) c1[bid] = red[0] + red[1] + red[2] + red[3];
        } else {
            int t = (bid - 256) * 256 + tid;   // < 6144
            int nb = t / 384, g = t % 384;
            const float* wrow = gWih + (long)nb * 49152 + (long)g * 128;
            const float* bp = bv + nb * 128;
            float acc = 0.f;
            for (int j = 0; j < 128; j++) acc += bp[j] * wrow[j];
            b1g[t] = acc;
        }
        return;
    }
    const float* in; short* out; int R, C, tx, ty;
    if (id < 256)       { int z = id >> 4, t = id & 15; in = mW1 + z * 16384; out = mW1T + z * 16384; R = 128; C = 128; tx = t & 3;  ty = t >> 2; }
    else if (id < 512)  { id -= 256; int z = id >> 4, t = id & 15; in = mW2 + z * 16384; out = mW2T + z * 16384; R = 128; C = 128; tx = t & 3;  ty = t >> 2; }
    else if (id < 576)  { id -= 512;  in = cW1; out = cW1T; R = 128; C = 512; tx = id & 15; ty = id >> 4; }
    else if (id < 832)  { id -= 576;  in = cW2; out = cW2T; R = 512; C = 512; tx = id & 15; ty = id >> 4; }
    else if (id < 1088) { id -= 832;  in = cW3; out = cW3T; R = 512; C = 512; tx = id & 15; ty = id >> 4; }
    else                { id -= 1088; in = cW4; out = cW4T; R = 512; C = 128; tx = id & 3;  ty = id >> 2; }
    __shared__ short t[32][33];
    int c0 = tx * 32, r0 = ty * 32;
    int x = threadIdx.x & 31, y = threadIdx.x >> 5;
    #pragma unroll
    for (int k = 0; k < 32; k += 8) t[y + k][x] = f2bfs(in[(long)(r0 + y + k) * C + (c0 + x)]);
    __syncthreads();
    #pragma unroll
    for (int k = 0; k < 32; k += 8) out[(long)(c0 + y + k) * R + (r0 + x)] = t[x][y + k];
}

// ---------------------------------------------------------------------------
// Tiled MFMA GEMM core (verified; m0/n0 explicit params).
// ---------------------------------------------------------------------------
template<int OUT_MODE, int RELU, int HAS_BIAS, int A_F32, int B_F32>
DEV void gemm_core(int m0, int n0,
                   const void* __restrict__ Av, long lda, long abase,
                   const void* __restrict__ Btv, long ldb, long bbase,
                   void* __restrict__ Cv, long ldc, long cbase,
                   const float* __restrict__ bias, long biasbase, int addbias,
                   int M, int N, int K, float scale, int kbeg, int kend,
                   short* As, short* Bs)
{
    const int tid  = threadIdx.x;
    const int wave = tid >> 6, lane = tid & 63;
    const int quad = lane >> 4, l16 = lane & 15;
    const int wr = (wave >> 1) * 32, wc = (wave & 1) * 32;

    f32x4 acc[2][2] = {};

    const int lrow = tid >> 2;
    const int lk   = (tid & 3) * 8;
    const int arow = imin(m0 + lrow, M - 1);
    const int brow = imin(n0 + lrow, N - 1);
    short* asd = &As[lrow * 40 + lk];
    short* bsd = &Bs[lrow * 40 + lk];

    short8 arS = {}, brS = {};
    f32x4 arF0 = {}, arF1 = {}, brF0 = {}, brF1 = {};

    auto loadA = [&](int k0) {
        if (A_F32) {
            const float* p = (const float*)Av + abase + (long)arow * lda + lk + k0;
            arF0 = *(const f32x4*)p; arF1 = *(const f32x4*)(p + 4);
        } else {
            arS = *(const short8*)((const short*)Av + abase + (long)arow * lda + lk + k0);
        }
    };
    auto loadB = [&](int k0) {
        if (B_F32) {
            const float* p = (const float*)Btv + bbase + (long)brow * ldb + lk + k0;
            brF0 = *(const f32x4*)p; brF1 = *(const f32x4*)(p + 4);
        } else {
            brS = *(const short8*)((const short*)Btv + bbase + (long)brow * ldb + lk + k0);
        }
    };
    auto stage = [&]() {
        if (A_F32) {
            short8 t;
            #pragma unroll
            for (int j = 0; j < 4; j++) { t[j] = f2bfs(arF0[j]); t[j + 4] = f2bfs(arF1[j]); }
            *(short8*)asd = t;
        } else *(short8*)asd = arS;
        if (B_F32) {
            short8 t;
            #pragma unroll
            for (int j = 0; j < 4; j++) { t[j] = f2bfs(brF0[j]); t[j + 4] = f2bfs(brF1[j]); }
            *(short8*)bsd = t;
        } else *(short8*)bsd = brS;
    };

    loadA(kbeg); loadB(kbeg);
    for (int k0 = kbeg; k0 < kend; k0 += 32) {
        stage();
        __syncthreads();
        if (k0 + 32 < kend) { loadA(k0 + 32); loadB(k0 + 32); }
        short8 a0 = *(const short8*)&As[(wr + l16) * 40 + quad * 8];
        short8 a1 = *(const short8*)&As[(wr + 16 + l16) * 40 + quad * 8];
        short8 b0 = *(const short8*)&Bs[(wc + l16) * 40 + quad * 8];
        short8 b1 = *(const short8*)&Bs[(wc + 16 + l16) * 40 + quad * 8];
        acc[0][0] = __builtin_amdgcn_mfma_f32_16x16x32_bf16(a0, b0, acc[0][0], 0, 0, 0);
        acc[0][1] = __builtin_amdgcn_mfma_f32_16x16x32_bf16(a0, b1, acc[0][1], 0, 0, 0);
        acc[1][0] = __builtin_amdgcn_mfma_f32_16x16x32_bf16(a1, b0, acc[1][0], 0, 0, 0);
        acc[1][1] = __builtin_amdgcn_mfma_f32_16x16x32_bf16(a1, b1, acc[1][1], 0, 0, 0);
        __syncthreads();
    }

    #pragma unroll
    for (int sr = 0; sr < 2; sr++) {
        #pragma unroll
        for (int sc = 0; sc < 2; sc++) {
            int gc = n0 + wc + sc * 16 + l16;
            if (gc >= N) continue;
            float bvv = 0.f;
            if (HAS_BIAS && addbias) bvv = bias[biasbase + gc];
            #pragma unroll
            for (int r = 0; r < 4; r++) {
                int gr = m0 + wr + sr * 16 + quad * 4 + r;
                if (gr >= M) continue;
                float v = acc[sr][sc][r] * scale + bvv;
                if (RELU) v = fmaxf(v, 0.f);
                long cidx = cbase + (long)gr * ldc + gc;
                if (OUT_MODE == 0)      ((float*)Cv)[cidx] = v;
                else if (OUT_MODE == 1) ((short*)Cv)[cidx] = f2bfs(v);
                else if (OUT_MODE == 2) ((float*)Cv)[cidx] += v;
                else                    atomicAdd((float*)Cv + cidx, v);
            }
        }
    }
}

template<int OUT_MODE, int RELU, int HAS_BIAS, int A_F32, int B_F32, int SPLITK>
__global__ __launch_bounds__(256) void gemm_bt(
    const void* __restrict__ Av, long lda, long aoff,
    const void* __restrict__ Btv, long ldb, long boff,
    void* __restrict__ Cv, long ldc, long coff,
    const float* __restrict__ bias, long biasoff,
    int M, int N, int K, float scale)
{
    __shared__ __align__(16) short As[64 * 40];
    __shared__ __align__(16) short Bs[64 * 40];
    const int bz = blockIdx.z;
    long abase, bbase, cbase, biasbase;
    int kbeg, kend, addbias;
    if (SPLITK > 1) {
        int ks = K / SPLITK;
        kbeg = bz * ks; kend = kbeg + ks;
        abase = 0; bbase = 0; cbase = 0; biasbase = 0; addbias = (bz == 0);
    } else {
        kbeg = 0; kend = K;
        abase = (long)bz * aoff; bbase = (long)bz * boff; cbase = (long)bz * coff;
        biasbase = (long)bz * biasoff; addbias = 1;
    }
    gemm_core<OUT_MODE, RELU, HAS_BIAS, A_F32, B_F32>(
        blockIdx.x * 64, blockIdx.y * 64,
        Av, lda, abase, Btv, ldb, bbase, Cv, ldc, cbase,
        bias, biasbase, addbias, M, N, K, scale, kbeg, kend, As, Bs);
}

// ---------------------------------------------------------------------------
// Prep 3 (one launch): M1 (bf16 in) | WvGT (bf16 in) | concept L0 | xt.
// blocks: [0,128) M1 | [128,512) WvGT | [512,640) conceptL0 | [640,8832) xt
// ---------------------------------------------------------------------------
__global__ __launch_bounds__(256) void prep3_k(
    const short* __restrict__ Wkbf, const short* __restrict__ Wqbf,
    short* __restrict__ M1bf,
    const short* __restrict__ gWihbf, const short* __restrict__ Wvbf,
    short* __restrict__ WvGTbf,
    const float* __restrict__ cvec, const short* __restrict__ cW1T,
    short* __restrict__ hA, const float* __restrict__ cb1,
    const short* __restrict__ xbf, short* __restrict__ xbfT)
{
    __shared__ __align__(16) char LDSU[10240];
    int bid = blockIdx.x;
    if (bid < 640) {
        short* As = (short*)LDSU; short* Bs = As + 2560;
        if (bid < 128) {
            gemm_core<1,0,0,0,0>((bid & 3) * 64, (bid >> 2) * 64,
                                 Wkbf, 2048, 0, Wqbf, 2048, 0, M1bf, 2048, 0,
                                 nullptr, 0, 1, 256, 2048, 2048, 1.f, 0, 2048, As, Bs);
        } else if (bid < 512) {
            int v2 = bid - 128;
            int x = v2 % 6, y = (v2 / 6) % 4, z = v2 / 24;
            gemm_core<1,0,0,0,0>(x * 64, y * 64,
                                 gWihbf, 128, (long)z * 49152, Wvbf, 2048, (long)z * 128,
                                 WvGTbf, 256, (long)z * 98304,
                                 nullptr, 0, 1, 384, 256, 128, 1.f, 0, 128, As, Bs);
        } else {
            int u = bid - 512;
            gemm_core<1,1,1,1,0>((u & 15) * 64, (u >> 4) * 64,
                                 cvec, 128, 0, cW1T, 128, 0, hA, 512, 0,
                                 cb1, 0, 1, 1024, 512, 128, 1.f, 0, 128, As, Bs);
        }
        return;
    }
    // xt: bf16 transpose per b (verified r8 xt_k body)
    int u = bid - 640;
    int x = u & 7, y = (u >> 3) & 31, b = u >> 8;
    short (*tl)[33] = (short(*)[33])LDSU;
    int i0 = x * 32, n0 = y * 32;
    int lx = threadIdx.x & 31, ly = threadIdx.x >> 5;
    const short* ip = xbf + (long)b * 262144;
    short* op = xbfT + (long)b * 262144;
    #pragma unroll
    for (int k = 0; k < 32; k += 8) tl[ly + k][lx] = ip[(long)(n0 + ly + k) * 256 + i0 + lx];
    __syncthreads();
    #pragma unroll
    for (int k = 0; k < 32; k += 8) op[(long)(i0 + ly + k) * 1024 + n0 + lx] = tl[lx][ly + k];
}

// gi = up @ WvGT + b1g  (z<16)  and  gh = slotsbf @ gWhh  (z>=16), one launch.
__global__ __launch_bounds__(256) void gemm_gigh(
    const float* __restrict__ up, const short* __restrict__ WvGT,
    const float* __restrict__ b1g,
    const short* __restrict__ slotsbf, const short* __restrict__ gWhh,
    float* __restrict__ gi, float* __restrict__ gh)
{
    __shared__ __align__(16) short As[64 * 40];
    __shared__ __align__(16) short Bs[64 * 40];
    int z = blockIdx.z;
    if (z < 16) {
        long nb = z;
        gemm_core<0, 0, 1, 1, 0>(blockIdx.x * 64, blockIdx.y * 64,
                                 up, 256, 0, WvGT, 256, nb * 98304,
                                 gi, 6144, nb * 384, b1g, nb * 384, 1,
                                 256, 384, 256, 1.f, 0, 256, As, Bs);
    } else {
        long nb = z - 16;
        gemm_core<0, 0, 0, 0, 0>(blockIdx.x * 64, blockIdx.y * 64,
                                 slotsbf, 2048, nb * 128, gWhh, 128, nb * 49152,
                                 gh, 6144, nb * 384, nullptr, 0, 1,
                                 256, 384, 128, 1.f, 0, 128, As, Bs);
    }
}

// ---------------------------------------------------------------------------
// LN of slots over 2048 -> s_ln bf16; raw slots -> bf16; zero kqf. Block/row.
// ---------------------------------------------------------------------------
template<int INIT>
__global__ __launch_bounds__(256) void ln_slots_k(float* __restrict__ slots,
                                                  const float* __restrict__ noise,
                                                  const float* __restrict__ mu,
                                                  const float* __restrict__ ls,
                                                  const float* __restrict__ g,
                                                  const float* __restrict__ b,
                                                  short* __restrict__ s_ln,
                                                  short* __restrict__ slotsbf,
                                                  float* __restrict__ kqf)
{
    int row = blockIdx.x, tid = threadIdx.x;
    kqf[row * 256 + tid] = 0.f;  // pre-zero for split-K atomic kq GEMM
    long base = (long)row * 2048 + tid * 8;
    float v[8];
    if (INIT) {
        #pragma unroll
        for (int k = 0; k < 8; k++) {
            int d = tid * 8 + k;
            v[k] = mu[d] + expf(ls[d]) * noise[base + k];
            slots[base + k] = v[k];
        }
    } else {
        *(f32x4*)&v[0] = *(const f32x4*)(slots + base);
        *(f32x4*)&v[4] = *(const f32x4*)(slots + base + 4);
    }
    float s = 0.f;
    #pragma unroll
    for (int k = 0; k < 8; k++) s += v[k];
    #pragma unroll
    for (int d = 1; d < 64; d <<= 1) s += __shfl_xor(s, d);
    __shared__ float wsum[4], wsq[4];
    int w = tid >> 6, lane = tid & 63;
    if (lane == 0) wsum[w] = s;
    __syncthreads();
    float mean = (wsum[0] + wsum[1] + wsum[2] + wsum[3]) * (1.f / 2048.f);
    float sq = 0.f;
    #pragma unroll
    for (int k = 0; k < 8; k++) { float dd = v[k] - mean; sq += dd * dd; }
    #pragma unroll
    for (int d = 1; d < 64; d <<= 1) sq += __shfl_xor(sq, d);
    if (lane == 0) wsq[w] = sq;
    __syncthreads();
    float var = (wsq[0] + wsq[1] + wsq[2] + wsq[3]) * (1.f / 2048.f);
    float inv = rsqrtf(var + 1e-5f);
    #pragma unroll
    for (int k = 0; k < 8; k++) {
        float xn = (v[k] - mean) * inv;
        s_ln[base + k]     = f2bfs(xn * g[tid * 8 + k] + b[tid * 8 + k]);
        slotsbf[base + k] = f2bfs(v[k]);
    }
}

// ---------------------------------------------------------------------------
// FUSED softmax + up-GEMM (verified r8).
// ---------------------------------------------------------------------------
template<int WRITE_ATTN>
__global__ __launch_bounds__(256) void up2_k(const float* __restrict__ dots,
                                             const short* __restrict__ xbfT,
                                             float* __restrict__ up,
                                             float* __restrict__ attng)
{
    int y = blockIdx.x, b = blockIdx.y, tid = threadIdx.x;
    int w = tid >> 6, lane = tid & 63, quad = lane >> 4, l16 = lane & 15;
    __shared__ __align__(16) short attn_l[8][1032];

    #pragma unroll
    for (int sw = 0; sw < 2; sw++) {
        int s = w * 2 + sw;
        const float* dp = dots + (long)b * 8192 + s;
        float v[16];
        float mx = -1e30f;
        #pragma unroll
        for (int k = 0; k < 16; k++) { v[k] = dp[(lane + k * 64) * 8]; mx = fmaxf(mx, v[k]); }
        #pragma unroll
        for (int d = 1; d < 64; d <<= 1) mx = fmaxf(mx, __shfl_xor(mx, d));
        float sum = 0.f;
        #pragma unroll
        for (int k = 0; k < 16; k++) { v[k] = expf(v[k] - mx); sum += v[k]; }
        #pragma unroll
        for (int d = 1; d < 64; d <<= 1) sum += __shfl_xor(sum, d);
        float inv = 1.f / sum;
        float sum2 = 0.f;
        #pragma unroll
        for (int k = 0; k < 16; k++) { v[k] = v[k] * inv + 1e-8f; sum2 += v[k]; }
        #pragma unroll
        for (int d = 1; d < 64; d <<= 1) sum2 += __shfl_xor(sum2, d);
        float inv2 = 1.f / sum2;
        #pragma unroll
        for (int k = 0; k < 16; k++) {
            float a = v[k] * inv2;
            int n = lane + k * 64;
            attn_l[s][n] = f2bfs(a);
            if (WRITE_ATTN && y == 0) attng[(long)b * 8192 + n * 8 + s] = a;
        }
    }
    __syncthreads();

    int c0 = y * 64 + w * 16;
    const short* bp = xbfT + (long)b * 262144 + (long)(c0 + l16) * 1024 + quad * 8;
    f32x4 acc = {};
    for (int ks = 0; ks < 32; ks++) {
        short8 a  = *(const short8*)&attn_l[l16 & 7][ks * 32 + quad * 8];
        short8 bb = *(const short8*)(bp + ks * 32);
        acc = __builtin_amdgcn_mfma_f32_16x16x32_bf16(a, bb, acc, 0, 0, 0);
    }
    #pragma unroll
    for (int r = 0; r < 4; r++) {
        int s = quad * 4 + r;
        if (s < 8) up[(long)b * 2048 + s * 256 + c0 + l16] = acc[r];
    }
}

// ---------------------------------------------------------------------------
// FUSED per-(nb,b) tail: GRU -> residual block-MLP -> BWA (verified r8).
// ---------------------------------------------------------------------------
template<int WRITE_OUT>
__global__ __launch_bounds__(512) void resid_bwa_k(
    float* __restrict__ slots,
    const float* __restrict__ gi, const float* __restrict__ gh,
    const float* __restrict__ bih, const float* __restrict__ bhh,
    const float* __restrict__ h4,
    const short* __restrict__ mW1T, const short* __restrict__ mW2T,
    const float* __restrict__ mb1, const float* __restrict__ mb2,
    float* __restrict__ outp)
{
    int nb = blockIdx.x, b = blockIdx.y, tid = threadIdx.x;
    int lane = tid & 63, r = tid >> 6;

    __shared__ __align__(16) float ml[64 * 132];
    __shared__ __align__(16) short wlds[8192];
    __shared__ __align__(16) float t1[8 * 128];
    __shared__ __align__(16) float t2[8 * 128];
    __shared__ __align__(16) float sc[8 * 64];

    {
        int p = tid >> 3, t8 = tid & 7;
        const float* src = h4 + (long)(p * 16 + nb) * 128 + t8 * 16;
        f32x4 a0 = *(const f32x4*)src;
        f32x4 a1 = *(const f32x4*)(src + 4);
        f32x4 a2 = *(const f32x4*)(src + 8);
        f32x4 a3 = *(const f32x4*)(src + 12);
        float s = 0.f, sq = 0.f;
        #pragma unroll
        for (int k = 0; k < 4; k++) {
            s  += a0[k] + a1[k] + a2[k] + a3[k];
            sq += a0[k]*a0[k] + a1[k]*a1[k] + a2[k]*a2[k] + a3[k]*a3[k];
        }
        #pragma unroll
        for (int d = 1; d < 8; d <<= 1) { s += __shfl_xor(s, d); sq += __shfl_xor(sq, d); }
        float mean = s * (1.f / 128.f);
        float var = sq * (1.f / 128.f) - mean * mean;
        float inv = rsqrtf(var + 1e-5f);
        float* dst = &ml[p * 132 + t8 * 16];
        #pragma unroll
        for (int k = 0; k < 4; k++) {
            dst[k]      = (a0[k] - mean) * inv;
            dst[4 + k]  = (a1[k] - mean) * inv;
            dst[8 + k]  = (a2[k] - mean) * inv;
            dst[12 + k] = (a3[k] - mean) * inv;
        }
    }

    auto stagew = [&](const short* Wh) {
        #pragma unroll
        for (int pass = 0; pass < 2; pass++) {
            int idx = pass * 4096 + tid * 8;
            short8 v = *(const short8*)(Wh + idx);
            int o = idx >> 7;
            int c = (idx >> 3) & 15;
            int key = (o & 15) ^ ((o >> 4) & 3);
            *(short8*)&wlds[o * 128 + ((c ^ key) << 3)] = v;
        }
    };
    stagew(mW1T + (long)nb * 16384);

    int row = b * 8 + r;
    long grow = (long)row * 6144 + nb * 384;
    long srow = (long)row * 2048 + nb * 128;
    int bb = nb * 384;
    float sv0, sv1;
    {
        float ir0 = gi[grow + lane]       + bih[bb + lane];
        float ir1 = gi[grow + lane + 64]  + bih[bb + lane + 64];
        float iz0 = gi[grow + 128 + lane] + bih[bb + 128 + lane];
        float iz1 = gi[grow + 192 + lane] + bih[bb + 192 + lane];
        float in0 = gi[grow + 256 + lane] + bih[bb + 256 + lane];
        float in1 = gi[grow + 320 + lane] + bih[bb + 320 + lane];
        float hr0 = gh[grow + lane]       + bhh[bb + lane];
        float hr1 = gh[grow + lane + 64]  + bhh[bb + lane + 64];
        float hz0 = gh[grow + 128 + lane] + bhh[bb + 128 + lane];
        float hz1 = gh[grow + 192 + lane] + bhh[bb + 192 + lane];
        float hn0 = gh[grow + 256 + lane] + bhh[bb + 256 + lane];
        float hn1 = gh[grow + 320 + lane] + bhh[bb + 320 + lane];
        float h0 = slots[srow + lane], h1 = slots[srow + lane + 64];
        float rg0 = sigm(ir0 + hr0), rg1 = sigm(ir1 + hr1);
        float zg0 = sigm(iz0 + hz0), zg1 = sigm(iz1 + hz1);
        sv0 = (1.f - zg0) * tanhf(in0 + rg0 * hn0) + zg0 * h0;
        sv1 = (1.f - zg1) * tanhf(in1 + rg1 * hn1) + zg1 * h1;
        float s = sv0 + sv1, sq = sv0 * sv0 + sv1 * sv1;
        #pragma unroll
        for (int d = 1; d < 64; d <<= 1) { s += __shfl_xor(s, d); sq += __shfl_xor(sq, d); }
        float mean = s * (1.f / 128.f);
        float var = sq * (1.f / 128.f) - mean * mean;
        float inv = rsqrtf(var + 1e-5f);
        t1[r * 128 + lane]      = (sv0 - mean) * inv;
        t1[r * 128 + lane + 64] = (sv1 - mean) * inv;
    }
    __syncthreads();

    auto mlpdot = [&](const float* xr) -> float {
        int key = (lane & 15) ^ ((lane >> 4) & 3);
        const short* wrow = &wlds[lane * 128];
        float acc0 = 0.f, acc1 = 0.f;
        #pragma unroll
        for (int c = 0; c < 16; c++) {
            f32x4 x0 = *(const f32x4*)(xr + c * 8);
            f32x4 x1 = *(const f32x4*)(xr + c * 8 + 4);
            short8 w = *(const short8*)(wrow + ((c ^ key) << 3));
            acc0 += x0[0]*bfs2f(w[0]) + x0[1]*bfs2f(w[1]) + x0[2]*bfs2f(w[2]) + x0[3]*bfs2f(w[3]);
            acc1 += x1[0]*bfs2f(w[4]) + x1[1]*bfs2f(w[5]) + x1[2]*bfs2f(w[6]) + x1[3]*bfs2f(w[7]);
        }
        return acc0 + acc1;
    };

    float c0 = mlpdot(&t1[r * 128]);
    __syncthreads();
    stagew(mW1T + (long)nb * 16384 + 8192);
    __syncthreads();
    float c1v = mlpdot(&t1[r * 128]);
    t2[r * 128 + lane]      = fmaxf(c0 + mb1[nb * 128 + lane], 0.f);
    t2[r * 128 + lane + 64] = fmaxf(c1v + mb1[nb * 128 + lane + 64], 0.f);
    __syncthreads();
    stagew(mW2T + (long)nb * 16384);
    __syncthreads();

    float y0 = mlpdot(&t2[r * 128]);
    __syncthreads();
    stagew(mW2T + (long)nb * 16384 + 8192);
    __syncthreads();
    float y1 = mlpdot(&t2[r * 128]);
    {
        y0 += mb2[nb * 128 + lane]      + sv0;
        y1 += mb2[nb * 128 + lane + 64] + sv1;
        float s = y0 + y1, sq = y0 * y0 + y1 * y1;
        #pragma unroll
        for (int d = 1; d < 64; d <<= 1) { s += __shfl_xor(s, d); sq += __shfl_xor(sq, d); }
        float mean = s * (1.f / 128.f);
        float var = sq * (1.f / 128.f) - mean * mean;
        float inv = rsqrtf(var + 1e-5f) * 0.08838834764831845f;
        t1[r * 128 + lane]      = (y0 - mean) * inv;
        t1[r * 128 + lane + 64] = (y1 - mean) * inv;
    }
    __syncthreads();

    {
        const float* qr = &t1[r * 128];
        const float* mr = &ml[lane * 132];
        float acc0 = 0.f, acc1 = 0.f;
        #pragma unroll
        for (int j = 0; j < 128; j += 8) {
            f32x4 q0 = *(const f32x4*)(qr + j);
            f32x4 q1 = *(const f32x4*)(qr + j + 4);
            f32x4 m0 = *(const f32x4*)(mr + j);
            f32x4 m1 = *(const f32x4*)(mr + j + 4);
            acc0 += q0[0]*m0[0] + q0[1]*m0[1] + q0[2]*m0[2] + q0[3]*m0[3];
            acc1 += q1[0]*m1[0] + q1[1]*m1[1] + q1[2]*m1[2] + q1[3]*m1[3];
        }
        float acc = acc0 + acc1;
        float mx = acc;
        #pragma unroll
        for (int d = 1; d < 64; d <<= 1) mx = fmaxf(mx, __shfl_xor(mx, d));
        float e = expf(acc - mx);
        float ss = e;
        #pragma unroll
        for (int d = 1; d < 64; d <<= 1) ss += __shfl_xor(ss, d);
        sc[r * 64 + lane] = e / ss;
    }
    __syncthreads();

    {
        const float* scr = &sc[r * 64];
        float a0 = 0.f, a1 = 0.f;
        #pragma unroll 4
        for (int p = 0; p < 64; p++) {
            float a = scr[p];
            a0 += a * ml[p * 132 + lane];
            a1 += a * ml[p * 132 + 64 + lane];
        }
        float* dst = slots + srow;
        dst[lane] = a0; dst[lane + 64] = a1;
        if (WRITE_OUT) {
            outp[srow + lane] = a0; outp[srow + lane + 64] = a1;
        }
    }
}

// ===========================================================================
extern "C" void kernel_launch(void* const* d_in, const int* in_sizes, int n_in,
                              void* d_out, int out_size, void* d_ws, size_t ws_size,
                              hipStream_t stream)
{
    (void)in_sizes; (void)n_in; (void)out_size; (void)ws_size;
    const float* inputs = (const float*)d_in[0];
    const float* noise  = (const float*)d_in[1];
    const float* smu    = (const float*)d_in[2];
    const float* sls    = (const float*)d_in[3];
    const float* Wq     = (const float*)d_in[4];
    const float* bq     = (const float*)d_in[5];
    const float* Wk     = (const float*)d_in[6];
    /* d_in[7] = bk: softmax(axis=n)-invariant; dropped */
    const float* Wv     = (const float*)d_in[8];
    const float* bv     = (const float*)d_in[9];
    const float* gWih   = (const float*)d_in[10];
    const float* gWhh   = (const float*)d_in[11];
    const float* gbih   = (const float*)d_in[12];
    const float* gbhh   = (const float*)d_in[13];
    const float* mW1    = (const float*)d_in[14];
    const float* mb1    = (const float*)d_in[15];
    const float* mW2    = (const float*)d_in[16];
    const float* mb2    = (const float*)d_in[17];
    const float* cvec   = (const float*)d_in[18];
    const float* cW1    = (const float*)d_in[19];
    const float* cb1    = (const float*)d_in[20];
    const float* cW2    = (const float*)d_in[21];
    const float* cb2    = (const float*)d_in[22];
    const float* cW3    = (const float*)d_in[23];
    const float* cb3    = (const float*)d_in[24];
    const float* cW4    = (const float*)d_in[25];
    const float* cb4    = (const float*)d_in[26];
    const float* nig    = (const float*)d_in[27];
    const float* nib    = (const float*)d_in[28];
    const float* nsg    = (const float*)d_in[29];
    const float* nsb    = (const float*)d_in[30];

    char* w = (char*)d_ws;
    auto take = [&](size_t bytes) -> char* {
        char* p = w;
        w += (bytes + 255) & ~(size_t)255;
        return p;
    };

    float* slots   = (float*)take((size_t)524288 * 4);
    short* xbf     = (short*)take((size_t)32768 * 256 * 2);
    short* xbfT    = (short*)take((size_t)32 * 256 * 1024 * 2);
    short* Wqbf    = (short*)take((size_t)2048 * 2048 * 2);
    short* Wkbf    = (short*)take((size_t)256 * 2048 * 2);
    short* Wvbf    = (short*)take((size_t)256 * 2048 * 2);
    short* gWihbf  = (short*)take((size_t)16 * 384 * 128 * 2);
    short* gWhhbf  = (short*)take((size_t)16 * 384 * 128 * 2);
    short* M1bf    = (short*)take((size_t)256 * 2048 * 2);
    short* WvGTbf  = (short*)take((size_t)16 * 384 * 256 * 2);
    float* b1g     = (float*)take((size_t)6144 * 4);
    float* c1      = (float*)take((size_t)256 * 4);
    short* mW1T    = (short*)take((size_t)16 * 128 * 128 * 2);
    short* mW2T    = (short*)take((size_t)16 * 128 * 128 * 2);
    short* cW1T    = (short*)take((size_t)512 * 128 * 2);
    short* cW2T    = (short*)take((size_t)512 * 512 * 2);
    short* cW3T    = (short*)take((size_t)512 * 512 * 2);
    short* cW4T    = (short*)take((size_t)128 * 512 * 2);
    short* hA      = (short*)take((size_t)1024 * 512 * 2);
    short* hB      = (short*)take((size_t)1024 * 512 * 2);
    float* h4      = (float*)take((size_t)1024 * 128 * 4);
    short* s_ln    = (short*)take((size_t)256 * 2048 * 2);
    short* slotsbf = (short*)take((size_t)256 * 2048 * 2);
    float* kqf     = (float*)take((size_t)256 * 256 * 4);
    float* dots    = (float*)take((size_t)32 * 1024 * 8 * 4);
    float* up      = (float*)take((size_t)256 * 256 * 4);
    float* gi      = (float*)take((size_t)256 * 6144 * 4);
    float* gh      = (float*)take((size_t)256 * 6144 * 4);

    float* out_slots = (float*)d_out;
    float* out_attn  = (float*)d_out + 524288;

    // --- prep ---------------------------------------------------------------
    cvt_ln_k<<<28672, 256, 0, stream>>>(Wq, Wk, Wv, gWih, gWhh,
                                        Wqbf, Wkbf, Wvbf, gWihbf, gWhhbf,
                                        inputs, nig, nib, xbf);
    transpose_b1c1_k<<<1432, 256, 0, stream>>>(mW1, mW2, cW1, cW2, cW3, cW4,
                                               mW1T, mW2T, cW1T, cW2T, cW3T, cW4T,
                                               bq, Wk, bv, gWih, c1, b1g);
    prep3_k<<<8832, 256, 0, stream>>>(Wkbf, Wqbf, M1bf, gWihbf, Wvbf, WvGTbf,
                                      cvec, cW1T, hA, cb1, xbf, xbfT);

    // --- concept memory L2..L4 (L1 fused into prep3) ------------------------
    gemm_bt<1,1,1,0,0,1><<<dim3(16, 8, 1), 256, 0, stream>>>(hA, 512, 0, cW2T, 512, 0, hB, 512, 0, cb2, 0, 1024, 512, 512, 1.f);
    gemm_bt<1,1,1,0,0,1><<<dim3(16, 8, 1), 256, 0, stream>>>(hB, 512, 0, cW3T, 512, 0, hA, 512, 0, cb3, 0, 1024, 512, 512, 1.f);
    gemm_bt<0,0,1,0,0,1><<<dim3(16, 2, 1), 256, 0, stream>>>(hA, 512, 0, cW4T, 512, 0, h4, 128, 0, cb4, 0, 1024, 128, 512, 1.f);

    for (int it = 0; it < 3; ++it) {
        if (it == 0)
            ln_slots_k<1><<<256, 256, 0, stream>>>(slots, noise, smu, sls, nsg, nsb, s_ln, slotsbf, kqf);
        else
            ln_slots_k<0><<<256, 256, 0, stream>>>(slots, noise, smu, sls, nsg, nsb, s_ln, slotsbf, kqf);
        // kq[bs,i] = s_ln @ M1T^T + c1   (split-K=8, f32 atomic)
        gemm_bt<3,0,1,0,0,8><<<dim3(4, 4, 8), 256, 0, stream>>>(
            s_ln, 2048, 0, M1bf, 2048, 0, kqf, 256, 0, c1, 0, 256, 256, 2048, 1.f);
        // dots[b,n,s] = scale * x[b] @ kq[b]^T
        gemm_bt<0,0,0,0,1,1><<<dim3(16, 1, 32), 256, 0, stream>>>(
            xbf, 256, 262144, kqf, 256, 2048, dots, 8, 8192, nullptr, 0, 1024, 8, 256, QSCALE);
        // fused softmax + up-GEMM
        if (it == 2)
            up2_k<1><<<dim3(4, 32), 256, 0, stream>>>(dots, xbfT, up, out_attn);
        else
            up2_k<0><<<dim3(4, 32), 256, 0, stream>>>(dots, xbfT, up, out_attn);
        // gi and gh in one launch
        gemm_gigh<<<dim3(4, 6, 32), 256, 0, stream>>>(up, WvGTbf, b1g, slotsbf, gWhhbf, gi, gh);
        // fused: GRU + residual block-MLP + BWA (+ direct out write last iter)
        if (it == 2)
            resid_bwa_k<1><<<dim3(16, 32), 512, 0, stream>>>(slots, gi, gh, gbih, gbhh,
                                                             h4, mW1T, mW2T, mb1, mb2, out_slots);
        else
            resid_bwa_k<0><<<dim3(16, 32), 512, 0, stream>>>(slots, gi, gh, gbih, gbhh,
                                                             h4, mW1T, mW2T, mb1, mb2, out_slots);
    }
}

// Round 13
// 385.859 us; speedup vs baseline: 1.1383x; 1.1383x over previous
//
#include <hip/hip_runtime.h>

typedef __attribute__((ext_vector_type(8))) short short8;
typedef __attribute__((ext_vector_type(4))) float f32x4;

#define DEV static __device__ __forceinline__
#define QSCALE 0.022097086912079608f

DEV float bfs2f(short s) {
    union { unsigned int u; float f; } c;
    c.u = ((unsigned int)(unsigned short)s) << 16;
    return c.f;
}
DEV short f2bfs(float f) {
    union { float f; unsigned int u; } c;
    c.f = f;
    unsigned int u = c.u;
    return (short)((u + 0x7fffu + ((u >> 16) & 1u)) >> 16);  // RNE
}
DEV int imin(int a, int b) { return a < b ? a : b; }
DEV float sigm(float x) { return 1.f / (1.f + expf(-x)); }

// ---------------------------------------------------------------------------
// Prep 1: f32->bf16 converts (Wq|Wk|Wv|gWih|gWhh) + LN of inputs.
// ---------------------------------------------------------------------------
__global__ __launch_bounds__(256) void cvt_ln_k(
    const float* __restrict__ Wq, const float* __restrict__ Wk, const float* __restrict__ Wv,
    const float* __restrict__ gih, const float* __restrict__ ghh,
    short* __restrict__ dWq, short* __restrict__ dWk, short* __restrict__ dWv,
    short* __restrict__ dgih, short* __restrict__ dghh,
    const float* __restrict__ inputs, const float* __restrict__ nig,
    const float* __restrict__ nib, short* __restrict__ xbf)
{
    if (blockIdx.x >= 26624) {
        int row  = (blockIdx.x - 26624) * 4 + (threadIdx.x >> 6);
        int lane = threadIdx.x & 63;
        long off = (long)row * 256 + lane * 4;
        f32x4 v4 = *(const f32x4*)(inputs + off);
        float v[4] = {v4[0], v4[1], v4[2], v4[3]};
        float s = v[0] + v[1] + v[2] + v[3];
        #pragma unroll
        for (int d = 1; d < 64; d <<= 1) s += __shfl_xor(s, d);
        float mean = s * (1.f / 256.f);
        float sq = 0.f;
        #pragma unroll
        for (int k = 0; k < 4; k++) { float dd = v[k] - mean; sq += dd * dd; }
        #pragma unroll
        for (int d = 1; d < 64; d <<= 1) sq += __shfl_xor(sq, d);
        float inv = rsqrtf(sq * (1.f / 256.f) + 1e-5f);
        short* op = xbf + off;
        #pragma unroll
        for (int k = 0; k < 4; k++)
            op[k] = f2bfs((v[k] - mean) * inv * nig[lane * 4 + k] + nib[lane * 4 + k]);
        return;
    }
    long i = (long)blockIdx.x * 256 + threadIdx.x;
    const float* s; short* d; long o;
    if      (i < 4194304) { s = Wq;  d = dWq;  o = i; }
    else if (i < 4718592) { s = Wk;  d = dWk;  o = i - 4194304; }
    else if (i < 5242880) { s = Wv;  d = dWv;  o = i - 4718592; }
    else if (i < 6029312) { s = gih; d = dgih; o = i - 5242880; }
    else                  { s = ghh; d = dghh; o = i - 6029312; }
    d[o] = f2bfs(s[o]);
}

// ---------------------------------------------------------------------------
// Prep 2: weight transposes + c1/b1g folded biases (verified r8).
// ---------------------------------------------------------------------------
__global__ __launch_bounds__(256) void transpose_b1c1_k(
    const float* __restrict__ mW1, const float* __restrict__ mW2,
    const float* __restrict__ cW1, const float* __restrict__ cW2,
    const float* __restrict__ cW3, const float* __restrict__ cW4,
    short* __restrict__ mW1T, short* __restrict__ mW2T,
    short* __restrict__ cW1T, short* __restrict__ cW2T,
    short* __restrict__ cW3T, short* __restrict__ cW4T,
    const float* __restrict__ bq, const float* __restrict__ Wk,
    const float* __restrict__ bv, const float* __restrict__ gWih,
    float* __restrict__ c1, float* __restrict__ b1g)
{
    int id = blockIdx.x, tid = threadIdx.x;
    if (id >= 1152) {
        int bid = id - 1152;
        __shared__ float red[4];
        if (bid < 256) {
            const float* row = Wk + (long)bid * 2048;
            float acc = 0.f;
            for (int d = tid; d < 2048; d += 256) acc += bq[d] * row[d];
            #pragma unroll
            for (int d = 1; d < 64; d <<= 1) acc += __shfl_xor(acc, d);
            int w = tid >> 6;
            if ((tid & 63) == 0) red[w] = acc;
            __syncthreads();
            if (tid == 0) c1[bid] = red[0] + red[1] + red[2] + red[3];
        } else {
            int t = (bid - 256) * 256 + tid;   // < 6144
            int nb = t / 384, g = t % 384;
            const float* wrow = gWih + (long)nb * 49152 + (long)g * 128;
            const float* bp = bv + nb * 128;
            float acc = 0.f;
            for (int j = 0; j < 128; j++) acc += bp[j] * wrow[j];
            b1g[t] = acc;
        }
        return;
    }
    const float* in; short* out; int R, C, tx, ty;
    if (id < 256)       { int z = id >> 4, t = id & 15; in = mW1 + z * 16384; out = mW1T + z * 16384; R = 128; C = 128; tx = t & 3;  ty = t >> 2; }
    else if (id < 512)  { id -= 256; int z = id >> 4, t = id & 15; in = mW2 + z * 16384; out = mW2T + z * 16384; R = 128; C = 128; tx = t & 3;  ty = t >> 2; }
    else if (id < 576)  { id -= 512;  in = cW1; out = cW1T; R = 128; C = 512; tx = id & 15; ty = id >> 4; }
    else if (id < 832)  { id -= 576;  in = cW2; out = cW2T; R = 512; C = 512; tx = id & 15; ty = id >> 4; }
    else if (id < 1088) { id -= 832;  in = cW3; out = cW3T; R = 512; C = 512; tx = id & 15; ty = id >> 4; }
    else                { id -= 1088; in = cW4; out = cW4T; R = 512; C = 128; tx = id & 3;  ty = id >> 2; }
    __shared__ short t[32][33];
    int c0 = tx * 32, r0 = ty * 32;
    int x = threadIdx.x & 31, y = threadIdx.x >> 5;
    #pragma unroll
    for (int k = 0; k < 32; k += 8) t[y + k][x] = f2bfs(in[(long)(r0 + y + k) * C + (c0 + x)]);
    __syncthreads();
    #pragma unroll
    for (int k = 0; k < 32; k += 8) out[(long)(c0 + y + k) * R + (r0 + x)] = t[x][y + k];
}

// ---------------------------------------------------------------------------
// Tiled MFMA GEMM core (verified; m0/n0 explicit params).
// ---------------------------------------------------------------------------
template<int OUT_MODE, int RELU, int HAS_BIAS, int A_F32, int B_F32>
DEV void gemm_core(int m0, int n0,
                   const void* __restrict__ Av, long lda, long abase,
                   const void* __restrict__ Btv, long ldb, long bbase,
                   void* __restrict__ Cv, long ldc, long cbase,
                   const float* __restrict__ bias, long biasbase, int addbias,
                   int M, int N, int K, float scale, int kbeg, int kend,
                   short* As, short* Bs)
{
    const int tid  = threadIdx.x;
    const int wave = tid >> 6, lane = tid & 63;
    const int quad = lane >> 4, l16 = lane & 15;
    const int wr = (wave >> 1) * 32, wc = (wave & 1) * 32;

    f32x4 acc[2][2] = {};

    const int lrow = tid >> 2;
    const int lk   = (tid & 3) * 8;
    const int arow = imin(m0 + lrow, M - 1);
    const int brow = imin(n0 + lrow, N - 1);
    short* asd = &As[lrow * 40 + lk];
    short* bsd = &Bs[lrow * 40 + lk];

    short8 arS = {}, brS = {};
    f32x4 arF0 = {}, arF1 = {}, brF0 = {}, brF1 = {};

    auto loadA = [&](int k0) {
        if (A_F32) {
            const float* p = (const float*)Av + abase + (long)arow * lda + lk + k0;
            arF0 = *(const f32x4*)p; arF1 = *(const f32x4*)(p + 4);
        } else {
            arS = *(const short8*)((const short*)Av + abase + (long)arow * lda + lk + k0);
        }
    };
    auto loadB = [&](int k0) {
        if (B_F32) {
            const float* p = (const float*)Btv + bbase + (long)brow * ldb + lk + k0;
            brF0 = *(const f32x4*)p; brF1 = *(const f32x4*)(p + 4);
        } else {
            brS = *(const short8*)((const short*)Btv + bbase + (long)brow * ldb + lk + k0);
        }
    };
    auto stage = [&]() {
        if (A_F32) {
            short8 t;
            #pragma unroll
            for (int j = 0; j < 4; j++) { t[j] = f2bfs(arF0[j]); t[j + 4] = f2bfs(arF1[j]); }
            *(short8*)asd = t;
        } else *(short8*)asd = arS;
        if (B_F32) {
            short8 t;
            #pragma unroll
            for (int j = 0; j < 4; j++) { t[j] = f2bfs(brF0[j]); t[j + 4] = f2bfs(brF1[j]); }
            *(short8*)bsd = t;
        } else *(short8*)bsd = brS;
    };

    loadA(kbeg); loadB(kbeg);
    for (int k0 = kbeg; k0 < kend; k0 += 32) {
        stage();
        __syncthreads();
        if (k0 + 32 < kend) { loadA(k0 + 32); loadB(k0 + 32); }
        short8 a0 = *(const short8*)&As[(wr + l16) * 40 + quad * 8];
        short8 a1 = *(const short8*)&As[(wr + 16 + l16) * 40 + quad * 8];
        short8 b0 = *(const short8*)&Bs[(wc + l16) * 40 + quad * 8];
        short8 b1 = *(const short8*)&Bs[(wc + 16 + l16) * 40 + quad * 8];
        acc[0][0] = __builtin_amdgcn_mfma_f32_16x16x32_bf16(a0, b0, acc[0][0], 0, 0, 0);
        acc[0][1] = __builtin_amdgcn_mfma_f32_16x16x32_bf16(a0, b1, acc[0][1], 0, 0, 0);
        acc[1][0] = __builtin_amdgcn_mfma_f32_16x16x32_bf16(a1, b0, acc[1][0], 0, 0, 0);
        acc[1][1] = __builtin_amdgcn_mfma_f32_16x16x32_bf16(a1, b1, acc[1][1], 0, 0, 0);
        __syncthreads();
    }

    #pragma unroll
    for (int sr = 0; sr < 2; sr++) {
        #pragma unroll
        for (int sc = 0; sc < 2; sc++) {
            int gc = n0 + wc + sc * 16 + l16;
            if (gc >= N) continue;
            float bvv = 0.f;
            if (HAS_BIAS && addbias) bvv = bias[biasbase + gc];
            #pragma unroll
            for (int r = 0; r < 4; r++) {
                int gr = m0 + wr + sr * 16 + quad * 4 + r;
                if (gr >= M) continue;
                float v = acc[sr][sc][r] * scale + bvv;
                if (RELU) v = fmaxf(v, 0.f);
                long cidx = cbase + (long)gr * ldc + gc;
                if (OUT_MODE == 0)      ((float*)Cv)[cidx] = v;
                else if (OUT_MODE == 1) ((short*)Cv)[cidx] = f2bfs(v);
                else if (OUT_MODE == 2) ((float*)Cv)[cidx] += v;
                else                    atomicAdd((float*)Cv + cidx, v);
            }
        }
    }
}

template<int OUT_MODE, int RELU, int HAS_BIAS, int A_F32, int B_F32, int SPLITK>
__global__ __launch_bounds__(256) void gemm_bt(
    const void* __restrict__ Av, long lda, long aoff,
    const void* __restrict__ Btv, long ldb, long boff,
    void* __restrict__ Cv, long ldc, long coff,
    const float* __restrict__ bias, long biasoff,
    int M, int N, int K, float scale)
{
    __shared__ __align__(16) short As[64 * 40];
    __shared__ __align__(16) short Bs[64 * 40];
    const int bz = blockIdx.z;
    long abase, bbase, cbase, biasbase;
    int kbeg, kend, addbias;
    if (SPLITK > 1) {
        int ks = K / SPLITK;
        kbeg = bz * ks; kend = kbeg + ks;
        abase = 0; bbase = 0; cbase = 0; biasbase = 0; addbias = (bz == 0);
    } else {
        kbeg = 0; kend = K;
        abase = (long)bz * aoff; bbase = (long)bz * boff; cbase = (long)bz * coff;
        biasbase = (long)bz * biasoff; addbias = 1;
    }
    gemm_core<OUT_MODE, RELU, HAS_BIAS, A_F32, B_F32>(
        blockIdx.x * 64, blockIdx.y * 64,
        Av, lda, abase, Btv, ldb, bbase, Cv, ldc, cbase,
        bias, biasbase, addbias, M, N, K, scale, kbeg, kend, As, Bs);
}

// ---------------------------------------------------------------------------
// Prep 3 (one launch): M1 (bf16 in) | WvGT (bf16 in) | concept L0 | xt.
// ---------------------------------------------------------------------------
__global__ __launch_bounds__(256) void prep3_k(
    const short* __restrict__ Wkbf, const short* __restrict__ Wqbf,
    short* __restrict__ M1bf,
    const short* __restrict__ gWihbf, const short* __restrict__ Wvbf,
    short* __restrict__ WvGTbf,
    const float* __restrict__ cvec, const short* __restrict__ cW1T,
    short* __restrict__ hA, const float* __restrict__ cb1,
    const short* __restrict__ xbf, short* __restrict__ xbfT)
{
    __shared__ __align__(16) char LDSU[10240];
    int bid = blockIdx.x;
    if (bid < 640) {
        short* As = (short*)LDSU; short* Bs = As + 2560;
        if (bid < 128) {
            gemm_core<1,0,0,0,0>((bid & 3) * 64, (bid >> 2) * 64,
                                 Wkbf, 2048, 0, Wqbf, 2048, 0, M1bf, 2048, 0,
                                 nullptr, 0, 1, 256, 2048, 2048, 1.f, 0, 2048, As, Bs);
        } else if (bid < 512) {
            int v2 = bid - 128;
            int x = v2 % 6, y = (v2 / 6) % 4, z = v2 / 24;
            gemm_core<1,0,0,0,0>(x * 64, y * 64,
                                 gWihbf, 128, (long)z * 49152, Wvbf, 2048, (long)z * 128,
                                 WvGTbf, 256, (long)z * 98304,
                                 nullptr, 0, 1, 384, 256, 128, 1.f, 0, 128, As, Bs);
        } else {
            int u = bid - 512;
            gemm_core<1,1,1,1,0>((u & 15) * 64, (u >> 4) * 64,
                                 cvec, 128, 0, cW1T, 128, 0, hA, 512, 0,
                                 cb1, 0, 1, 1024, 512, 128, 1.f, 0, 128, As, Bs);
        }
        return;
    }
    int u = bid - 640;
    int x = u & 7, y = (u >> 3) & 31, b = u >> 8;
    short (*tl)[33] = (short(*)[33])LDSU;
    int i0 = x * 32, n0 = y * 32;
    int lx = threadIdx.x & 31, ly = threadIdx.x >> 5;
    const short* ip = xbf + (long)b * 262144;
    short* op = xbfT + (long)b * 262144;
    #pragma unroll
    for (int k = 0; k < 32; k += 8) tl[ly + k][lx] = ip[(long)(n0 + ly + k) * 256 + i0 + lx];
    __syncthreads();
    #pragma unroll
    for (int k = 0; k < 32; k += 8) op[(long)(i0 + ly + k) * 1024 + n0 + lx] = tl[lx][ly + k];
}

// gi = up @ WvGT + b1g  (z<16)  and  gh = slotsbf @ gWhh  (z>=16), one launch.
__global__ __launch_bounds__(256) void gemm_gigh(
    const float* __restrict__ up, const short* __restrict__ WvGT,
    const float* __restrict__ b1g,
    const short* __restrict__ slotsbf, const short* __restrict__ gWhh,
    float* __restrict__ gi, float* __restrict__ gh)
{
    __shared__ __align__(16) short As[64 * 40];
    __shared__ __align__(16) short Bs[64 * 40];
    int z = blockIdx.z;
    if (z < 16) {
        long nb = z;
        gemm_core<0, 0, 1, 1, 0>(blockIdx.x * 64, blockIdx.y * 64,
                                 up, 256, 0, WvGT, 256, nb * 98304,
                                 gi, 6144, nb * 384, b1g, nb * 384, 1,
                                 256, 384, 256, 1.f, 0, 256, As, Bs);
    } else {
        long nb = z - 16;
        gemm_core<0, 0, 0, 0, 0>(blockIdx.x * 64, blockIdx.y * 64,
                                 slotsbf, 2048, nb * 128, gWhh, 128, nb * 49152,
                                 gh, 6144, nb * 384, nullptr, 0, 1,
                                 256, 384, 128, 1.f, 0, 128, As, Bs);
    }
}

// ---------------------------------------------------------------------------
// LN of slots over 2048 -> s_ln bf16; raw slots -> bf16; zero kqf. Block/row.
// ---------------------------------------------------------------------------
template<int INIT>
__global__ __launch_bounds__(256) void ln_slots_k(float* __restrict__ slots,
                                                  const float* __restrict__ noise,
                                                  const float* __restrict__ mu,
                                                  const float* __restrict__ ls,
                                                  const float* __restrict__ g,
                                                  const float* __restrict__ b,
                                                  short* __restrict__ s_ln,
                                                  short* __restrict__ slotsbf,
                                                  float* __restrict__ kqf)
{
    int row = blockIdx.x, tid = threadIdx.x;
    kqf[row * 256 + tid] = 0.f;  // pre-zero for split-K atomic kq GEMM
    long base = (long)row * 2048 + tid * 8;
    float v[8];
    if (INIT) {
        #pragma unroll
        for (int k = 0; k < 8; k++) {
            int d = tid * 8 + k;
            v[k] = mu[d] + expf(ls[d]) * noise[base + k];
            slots[base + k] = v[k];
        }
    } else {
        *(f32x4*)&v[0] = *(const f32x4*)(slots + base);
        *(f32x4*)&v[4] = *(const f32x4*)(slots + base + 4);
    }
    float s = 0.f;
    #pragma unroll
    for (int k = 0; k < 8; k++) s += v[k];
    #pragma unroll
    for (int d = 1; d < 64; d <<= 1) s += __shfl_xor(s, d);
    __shared__ float wsum[4], wsq[4];
    int w = tid >> 6, lane = tid & 63;
    if (lane == 0) wsum[w] = s;
    __syncthreads();
    float mean = (wsum[0] + wsum[1] + wsum[2] + wsum[3]) * (1.f / 2048.f);
    float sq = 0.f;
    #pragma unroll
    for (int k = 0; k < 8; k++) { float dd = v[k] - mean; sq += dd * dd; }
    #pragma unroll
    for (int d = 1; d < 64; d <<= 1) sq += __shfl_xor(sq, d);
    if (lane == 0) wsq[w] = sq;
    __syncthreads();
    float var = (wsq[0] + wsq[1] + wsq[2] + wsq[3]) * (1.f / 2048.f);
    float inv = rsqrtf(var + 1e-5f);
    #pragma unroll
    for (int k = 0; k < 8; k++) {
        float xn = (v[k] - mean) * inv;
        s_ln[base + k]     = f2bfs(xn * g[tid * 8 + k] + b[tid * 8 + k]);
        slotsbf[base + k] = f2bfs(v[k]);
    }
}

// ---------------------------------------------------------------------------
// FUSED softmax + up-GEMM (verified r8).
// ---------------------------------------------------------------------------
template<int WRITE_ATTN>
__global__ __launch_bounds__(256) void up2_k(const float* __restrict__ dots,
                                             const short* __restrict__ xbfT,
                                             float* __restrict__ up,
                                             float* __restrict__ attng)
{
    int y = blockIdx.x, b = blockIdx.y, tid = threadIdx.x;
    int w = tid >> 6, lane = tid & 63, quad = lane >> 4, l16 = lane & 15;
    __shared__ __align__(16) short attn_l[8][1032];

    #pragma unroll
    for (int sw = 0; sw < 2; sw++) {
        int s = w * 2 + sw;
        const float* dp = dots + (long)b * 8192 + s;
        float v[16];
        float mx = -1e30f;
        #pragma unroll
        for (int k = 0; k < 16; k++) { v[k] = dp[(lane + k * 64) * 8]; mx = fmaxf(mx, v[k]); }
        #pragma unroll
        for (int d = 1; d < 64; d <<= 1) mx = fmaxf(mx, __shfl_xor(mx, d));
        float sum = 0.f;
        #pragma unroll
        for (int k = 0; k < 16; k++) { v[k] = expf(v[k] - mx); sum += v[k]; }
        #pragma unroll
        for (int d = 1; d < 64; d <<= 1) sum += __shfl_xor(sum, d);
        float inv = 1.f / sum;
        float sum2 = 0.f;
        #pragma unroll
        for (int k = 0; k < 16; k++) { v[k] = v[k] * inv + 1e-8f; sum2 += v[k]; }
        #pragma unroll
        for (int d = 1; d < 64; d <<= 1) sum2 += __shfl_xor(sum2, d);
        float inv2 = 1.f / sum2;
        #pragma unroll
        for (int k = 0; k < 16; k++) {
            float a = v[k] * inv2;
            int n = lane + k * 64;
            attn_l[s][n] = f2bfs(a);
            if (WRITE_ATTN && y == 0) attng[(long)b * 8192 + n * 8 + s] = a;
        }
    }
    __syncthreads();

    int c0 = y * 64 + w * 16;
    const short* bp = xbfT + (long)b * 262144 + (long)(c0 + l16) * 1024 + quad * 8;
    f32x4 acc = {};
    for (int ks = 0; ks < 32; ks++) {
        short8 a  = *(const short8*)&attn_l[l16 & 7][ks * 32 + quad * 8];
        short8 bb = *(const short8*)(bp + ks * 32);
        acc = __builtin_amdgcn_mfma_f32_16x16x32_bf16(a, bb, acc, 0, 0, 0);
    }
    #pragma unroll
    for (int r = 0; r < 4; r++) {
        int s = quad * 4 + r;
        if (s < 8) up[(long)b * 2048 + s * 256 + c0 + l16] = acc[r];
    }
}

// ---------------------------------------------------------------------------
// FUSED per-(nb,b) tail: GRU -> residual block-MLP (MFMA) -> BWA.
// Phases A/B/E/F/G identical to verified r8; the MLP core now runs on MFMA:
//   t1b (bf16, pad 136) -> [W1 MFMA, bias+relu] -> t2b -> [W2 MFMA] -> yb f32
// Wave w owns output cols w*16..w*16+15; A-frag row = l16&7 (dup-row trick,
// verified in up2_k); B-frags read direct from mW1T/mW2T (L2-hot, 32x reuse).
// ---------------------------------------------------------------------------
template<int WRITE_OUT>
__global__ __launch_bounds__(512) void resid_bwa_k(
    float* __restrict__ slots,
    const float* __restrict__ gi, const float* __restrict__ gh,
    const float* __restrict__ bih, const float* __restrict__ bhh,
    const float* __restrict__ h4,
    const short* __restrict__ mW1T, const short* __restrict__ mW2T,
    const float* __restrict__ mb1, const float* __restrict__ mb2,
    float* __restrict__ outp)
{
    int nb = blockIdx.x, b = blockIdx.y, tid = threadIdx.x;
    int lane = tid & 63, r = tid >> 6;
    int quad = lane >> 4, l16 = lane & 15;

    __shared__ __align__(16) float ml[64 * 132];    // 33792 B
    __shared__ __align__(16) short t1b[8 * 136];    // 2176 B  bf16 BLN(slots')
    __shared__ __align__(16) short t2b[8 * 136];    // 2176 B  bf16 relu(layer1)
    __shared__ __align__(16) float yb[8 * 132];     // 4224 B  raw layer2 out
    __shared__ __align__(16) float t1[8 * 128];     // 4096 B  qn (phase E)
    __shared__ __align__(16) float sc[8 * 64];      // 2048 B

    // Phase A: ml = BLN(h4 rows for this nb). 8 threads per proto row.
    {
        int p = tid >> 3, t8 = tid & 7;
        const float* src = h4 + (long)(p * 16 + nb) * 128 + t8 * 16;
        f32x4 a0 = *(const f32x4*)src;
        f32x4 a1 = *(const f32x4*)(src + 4);
        f32x4 a2 = *(const f32x4*)(src + 8);
        f32x4 a3 = *(const f32x4*)(src + 12);
        float s = 0.f, sq = 0.f;
        #pragma unroll
        for (int k = 0; k < 4; k++) {
            s  += a0[k] + a1[k] + a2[k] + a3[k];
            sq += a0[k]*a0[k] + a1[k]*a1[k] + a2[k]*a2[k] + a3[k]*a3[k];
        }
        #pragma unroll
        for (int d = 1; d < 8; d <<= 1) { s += __shfl_xor(s, d); sq += __shfl_xor(sq, d); }
        float mean = s * (1.f / 128.f);
        float var = sq * (1.f / 128.f) - mean * mean;
        float inv = rsqrtf(var + 1e-5f);
        float* dst = &ml[p * 132 + t8 * 16];
        #pragma unroll
        for (int k = 0; k < 4; k++) {
            dst[k]      = (a0[k] - mean) * inv;
            dst[4 + k]  = (a1[k] - mean) * inv;
            dst[8 + k]  = (a2[k] - mean) * inv;
            dst[12 + k] = (a3[k] - mean) * inv;
        }
    }

    // Phase B: GRU -> sv (regs); BLN -> t1b (bf16). r8-verified math.
    int row = b * 8 + r;
    long grow = (long)row * 6144 + nb * 384;
    long srow = (long)row * 2048 + nb * 128;
    int bb = nb * 384;
    float sv0, sv1;
    {
        float ir0 = gi[grow + lane]       + bih[bb + lane];
        float ir1 = gi[grow + lane + 64]  + bih[bb + lane + 64];
        float iz0 = gi[grow + 128 + lane] + bih[bb + 128 + lane];
        float iz1 = gi[grow + 192 + lane] + bih[bb + 192 + lane];
        float in0 = gi[grow + 256 + lane] + bih[bb + 256 + lane];
        float in1 = gi[grow + 320 + lane] + bih[bb + 320 + lane];
        float hr0 = gh[grow + lane]       + bhh[bb + lane];
        float hr1 = gh[grow + lane + 64]  + bhh[bb + lane + 64];
        float hz0 = gh[grow + 128 + lane] + bhh[bb + 128 + lane];
        float hz1 = gh[grow + 192 + lane] + bhh[bb + 192 + lane];
        float hn0 = gh[grow + 256 + lane] + bhh[bb + 256 + lane];
        float hn1 = gh[grow + 320 + lane] + bhh[bb + 320 + lane];
        float h0 = slots[srow + lane], h1 = slots[srow + lane + 64];
        float rg0 = sigm(ir0 + hr0), rg1 = sigm(ir1 + hr1);
        float zg0 = sigm(iz0 + hz0), zg1 = sigm(iz1 + hz1);
        sv0 = (1.f - zg0) * tanhf(in0 + rg0 * hn0) + zg0 * h0;
        sv1 = (1.f - zg1) * tanhf(in1 + rg1 * hn1) + zg1 * h1;
        float s = sv0 + sv1, sq = sv0 * sv0 + sv1 * sv1;
        #pragma unroll
        for (int d = 1; d < 64; d <<= 1) { s += __shfl_xor(s, d); sq += __shfl_xor(sq, d); }
        float mean = s * (1.f / 128.f);
        float var = sq * (1.f / 128.f) - mean * mean;
        float inv = rsqrtf(var + 1e-5f);
        t1b[r * 136 + lane]      = f2bfs((sv0 - mean) * inv);
        t1b[r * 136 + lane + 64] = f2bfs((sv1 - mean) * inv);
    }
    __syncthreads();

    // Phase C: layer1 via MFMA. wave r -> cols col0..col0+15.
    int col = r * 16 + l16;
    {
        const short* bp = mW1T + (long)nb * 16384 + (long)col * 128 + quad * 8;
        const short* ap = &t1b[(l16 & 7) * 136 + quad * 8];
        f32x4 acc = {};
        #pragma unroll
        for (int ks = 0; ks < 4; ks++) {
            short8 a  = *(const short8*)(ap + ks * 32);
            short8 bv = *(const short8*)(bp + ks * 32);
            acc = __builtin_amdgcn_mfma_f32_16x16x32_bf16(a, bv, acc, 0, 0, 0);
        }
        float bias1 = mb1[nb * 128 + col];
        #pragma unroll
        for (int rr = 0; rr < 4; rr++) {
            int orow = quad * 4 + rr;
            if (orow < 8) t2b[orow * 136 + col] = f2bfs(fmaxf(acc[rr] + bias1, 0.f));
        }
    }
    __syncthreads();

    // Phase D: layer2 via MFMA -> yb (raw f32).
    {
        const short* bp = mW2T + (long)nb * 16384 + (long)col * 128 + quad * 8;
        const short* ap = &t2b[(l16 & 7) * 136 + quad * 8];
        f32x4 acc = {};
        #pragma unroll
        for (int ks = 0; ks < 4; ks++) {
            short8 a  = *(const short8*)(ap + ks * 32);
            short8 bv = *(const short8*)(bp + ks * 32);
            acc = __builtin_amdgcn_mfma_f32_16x16x32_bf16(a, bv, acc, 0, 0, 0);
        }
        #pragma unroll
        for (int rr = 0; rr < 4; rr++) {
            int orow = quad * 4 + rr;
            if (orow < 8) yb[orow * 132 + col] = acc[rr];
        }
    }
    __syncthreads();

    // Phase D2: residual + BLN*scale -> qn (t1). Original per-thread mapping.
    {
        float y0 = yb[r * 132 + lane]      + mb2[nb * 128 + lane]      + sv0;
        float y1 = yb[r * 132 + lane + 64] + mb2[nb * 128 + lane + 64] + sv1;
        float s = y0 + y1, sq = y0 * y0 + y1 * y1;
        #pragma unroll
        for (int d = 1; d < 64; d <<= 1) { s += __shfl_xor(s, d); sq += __shfl_xor(sq, d); }
        float mean = s * (1.f / 128.f);
        float var = sq * (1.f / 128.f) - mean * mean;
        float inv = rsqrtf(var + 1e-5f) * 0.08838834764831845f;
        t1[r * 128 + lane]      = (y0 - mean) * inv;
        t1[r * 128 + lane + 64] = (y1 - mean) * inv;
    }
    __syncthreads();

    // Phase E+F: scores + softmax (wave r handles its own slot row; p=lane)
    {
        const float* qr = &t1[r * 128];
        const float* mr = &ml[lane * 132];
        float acc0 = 0.f, acc1 = 0.f;
        #pragma unroll
        for (int j = 0; j < 128; j += 8) {
            f32x4 q0 = *(const f32x4*)(qr + j);
            f32x4 q1 = *(const f32x4*)(qr + j + 4);
            f32x4 m0 = *(const f32x4*)(mr + j);
            f32x4 m1 = *(const f32x4*)(mr + j + 4);
            acc0 += q0[0]*m0[0] + q0[1]*m0[1] + q0[2]*m0[2] + q0[3]*m0[3];
            acc1 += q1[0]*m1[0] + q1[1]*m1[1] + q1[2]*m1[2] + q1[3]*m1[3];
        }
        float acc = acc0 + acc1;
        float mx = acc;
        #pragma unroll
        for (int d = 1; d < 64; d <<= 1) mx = fmaxf(mx, __shfl_xor(mx, d));
        float e = expf(acc - mx);
        float ss = e;
        #pragma unroll
        for (int d = 1; d < 64; d <<= 1) ss += __shfl_xor(ss, d);
        sc[r * 64 + lane] = e / ss;
    }
    __syncthreads();

    // Phase G: slots = attn @ mem
    {
        const float* scr = &sc[r * 64];
        float a0 = 0.f, a1 = 0.f;
        #pragma unroll 4
        for (int p = 0; p < 64; p++) {
            float a = scr[p];
            a0 += a * ml[p * 132 + lane];
            a1 += a * ml[p * 132 + 64 + lane];
        }
        float* dst = slots + srow;
        dst[lane] = a0; dst[lane + 64] = a1;
        if (WRITE_OUT) {
            outp[srow + lane] = a0; outp[srow + lane + 64] = a1;
        }
    }
}

// ===========================================================================
extern "C" void kernel_launch(void* const* d_in, const int* in_sizes, int n_in,
                              void* d_out, int out_size, void* d_ws, size_t ws_size,
                              hipStream_t stream)
{
    (void)in_sizes; (void)n_in; (void)out_size; (void)ws_size;
    const float* inputs = (const float*)d_in[0];
    const float* noise  = (const float*)d_in[1];
    const float* smu    = (const float*)d_in[2];
    const float* sls    = (const float*)d_in[3];
    const float* Wq     = (const float*)d_in[4];
    const float* bq     = (const float*)d_in[5];
    const float* Wk     = (const float*)d_in[6];
    /* d_in[7] = bk: softmax(axis=n)-invariant; dropped */
    const float* Wv     = (const float*)d_in[8];
    const float* bv     = (const float*)d_in[9];
    const float* gWih   = (const float*)d_in[10];
    const float* gWhh   = (const float*)d_in[11];
    const float* gbih   = (const float*)d_in[12];
    const float* gbhh   = (const float*)d_in[13];
    const float* mW1    = (const float*)d_in[14];
    const float* mb1    = (const float*)d_in[15];
    const float* mW2    = (const float*)d_in[16];
    const float* mb2    = (const float*)d_in[17];
    const float* cvec   = (const float*)d_in[18];
    const float* cW1    = (const float*)d_in[19];
    const float* cb1    = (const float*)d_in[20];
    const float* cW2    = (const float*)d_in[21];
    const float* cb2    = (const float*)d_in[22];
    const float* cW3    = (const float*)d_in[23];
    const float* cb3    = (const float*)d_in[24];
    const float* cW4    = (const float*)d_in[25];
    const float* cb4    = (const float*)d_in[26];
    const float* nig    = (const float*)d_in[27];
    const float* nib    = (const float*)d_in[28];
    const float* nsg    = (const float*)d_in[29];
    const float* nsb    = (const float*)d_in[30];

    char* w = (char*)d_ws;
    auto take = [&](size_t bytes) -> char* {
        char* p = w;
        w += (bytes + 255) & ~(size_t)255;
        return p;
    };

    float* slots   = (float*)take((size_t)524288 * 4);
    short* xbf     = (short*)take((size_t)32768 * 256 * 2);
    short* xbfT    = (short*)take((size_t)32 * 256 * 1024 * 2);
    short* Wqbf    = (short*)take((size_t)2048 * 2048 * 2);
    short* Wkbf    = (short*)take((size_t)256 * 2048 * 2);
    short* Wvbf    = (short*)take((size_t)256 * 2048 * 2);
    short* gWihbf  = (short*)take((size_t)16 * 384 * 128 * 2);
    short* gWhhbf  = (short*)take((size_t)16 * 384 * 128 * 2);
    short* M1bf    = (short*)take((size_t)256 * 2048 * 2);
    short* WvGTbf  = (short*)take((size_t)16 * 384 * 256 * 2);
    float* b1g     = (float*)take((size_t)6144 * 4);
    float* c1      = (float*)take((size_t)256 * 4);
    short* mW1T    = (short*)take((size_t)16 * 128 * 128 * 2);
    short* mW2T    = (short*)take((size_t)16 * 128 * 128 * 2);
    short* cW1T    = (short*)take((size_t)512 * 128 * 2);
    short* cW2T    = (short*)take((size_t)512 * 512 * 2);
    short* cW3T    = (short*)take((size_t)512 * 512 * 2);
    short* cW4T    = (short*)take((size_t)128 * 512 * 2);
    short* hA      = (short*)take((size_t)1024 * 512 * 2);
    short* hB      = (short*)take((size_t)1024 * 512 * 2);
    float* h4      = (float*)take((size_t)1024 * 128 * 4);
    short* s_ln    = (short*)take((size_t)256 * 2048 * 2);
    short* slotsbf = (short*)take((size_t)256 * 2048 * 2);
    float* kqf     = (float*)take((size_t)256 * 256 * 4);
    float* dots    = (float*)take((size_t)32 * 1024 * 8 * 4);
    float* up      = (float*)take((size_t)256 * 256 * 4);
    float* gi      = (float*)take((size_t)256 * 6144 * 4);
    float* gh      = (float*)take((size_t)256 * 6144 * 4);

    float* out_slots = (float*)d_out;
    float* out_attn  = (float*)d_out + 524288;

    // --- prep ---------------------------------------------------------------
    cvt_ln_k<<<28672, 256, 0, stream>>>(Wq, Wk, Wv, gWih, gWhh,
                                        Wqbf, Wkbf, Wvbf, gWihbf, gWhhbf,
                                        inputs, nig, nib, xbf);
    transpose_b1c1_k<<<1432, 256, 0, stream>>>(mW1, mW2, cW1, cW2, cW3, cW4,
                                               mW1T, mW2T, cW1T, cW2T, cW3T, cW4T,
                                               bq, Wk, bv, gWih, c1, b1g);
    prep3_k<<<8832, 256, 0, stream>>>(Wkbf, Wqbf, M1bf, gWihbf, Wvbf, WvGTbf,
                                      cvec, cW1T, hA, cb1, xbf, xbfT);

    // --- concept memory L2..L4 (L1 fused into prep3) ------------------------
    gemm_bt<1,1,1,0,0,1><<<dim3(16, 8, 1), 256, 0, stream>>>(hA, 512, 0, cW2T, 512, 0, hB, 512, 0, cb2, 0, 1024, 512, 512, 1.f);
    gemm_bt<1,1,1,0,0,1><<<dim3(16, 8, 1), 256, 0, stream>>>(hB, 512, 0, cW3T, 512, 0, hA, 512, 0, cb3, 0, 1024, 512, 512, 1.f);
    gemm_bt<0,0,1,0,0,1><<<dim3(16, 2, 1), 256, 0, stream>>>(hA, 512, 0, cW4T, 512, 0, h4, 128, 0, cb4, 0, 1024, 128, 512, 1.f);

    for (int it = 0; it < 3; ++it) {
        if (it == 0)
            ln_slots_k<1><<<256, 256, 0, stream>>>(slots, noise, smu, sls, nsg, nsb, s_ln, slotsbf, kqf);
        else
            ln_slots_k<0><<<256, 256, 0, stream>>>(slots, noise, smu, sls, nsg, nsb, s_ln, slotsbf, kqf);
        // kq[bs,i] = s_ln @ M1T^T + c1   (split-K=8, f32 atomic)
        gemm_bt<3,0,1,0,0,8><<<dim3(4, 4, 8), 256, 0, stream>>>(
            s_ln, 2048, 0, M1bf, 2048, 0, kqf, 256, 0, c1, 0, 256, 256, 2048, 1.f);
        // dots[b,n,s] = scale * x[b] @ kq[b]^T
        gemm_bt<0,0,0,0,1,1><<<dim3(16, 1, 32), 256, 0, stream>>>(
            xbf, 256, 262144, kqf, 256, 2048, dots, 8, 8192, nullptr, 0, 1024, 8, 256, QSCALE);
        // fused softmax + up-GEMM
        if (it == 2)
            up2_k<1><<<dim3(4, 32), 256, 0, stream>>>(dots, xbfT, up, out_attn);
        else
            up2_k<0><<<dim3(4, 32), 256, 0, stream>>>(dots, xbfT, up, out_attn);
        // gi and gh in one launch
        gemm_gigh<<<dim3(4, 6, 32), 256, 0, stream>>>(up, WvGTbf, b1g, slotsbf, gWhhbf, gi, gh);
        // fused: GRU + residual block-MLP (MFMA) + BWA (+ direct out last iter)
        if (it == 2)
            resid_bwa_k<1><<<dim3(16, 32), 512, 0, stream>>>(slots, gi, gh, gbih, gbhh,
                                                             h4, mW1T, mW2T, mb1, mb2, out_slots);
        else
            resid_bwa_k<0><<<dim3(16, 32), 512, 0, stream>>>(slots, gi, gh, gbih, gbhh,
                                                             h4, mW1T, mW2T, mb1, mb2, out_slots);
    }
}

// Round 14
// 379.594 us; speedup vs baseline: 1.1570x; 1.0165x over previous
//
#include <hip/hip_runtime.h>

typedef __attribute__((ext_vector_type(8))) short short8;
typedef __attribute__((ext_vector_type(4))) float f32x4;

#define DEV static __device__ __forceinline__
#define QSCALE 0.022097086912079608f

DEV float bfs2f(short s) {
    union { unsigned int u; float f; } c;
    c.u = ((unsigned int)(unsigned short)s) << 16;
    return c.f;
}
DEV short f2bfs(float f) {
    union { float f; unsigned int u; } c;
    c.f = f;
    unsigned int u = c.u;
    return (short)((u + 0x7fffu + ((u >> 16) & 1u)) >> 16);  // RNE
}
DEV int imin(int a, int b) { return a < b ? a : b; }
DEV float sigm(float x) { return 1.f / (1.f + expf(-x)); }

// ---------------------------------------------------------------------------
// Prep 1: f32->bf16 converts (Wq|Wk|Wv|gWih|gWhh) + LN of inputs.
// ---------------------------------------------------------------------------
__global__ __launch_bounds__(256) void cvt_ln_k(
    const float* __restrict__ Wq, const float* __restrict__ Wk, const float* __restrict__ Wv,
    const float* __restrict__ gih, const float* __restrict__ ghh,
    short* __restrict__ dWq, short* __restrict__ dWk, short* __restrict__ dWv,
    short* __restrict__ dgih, short* __restrict__ dghh,
    const float* __restrict__ inputs, const float* __restrict__ nig,
    const float* __restrict__ nib, short* __restrict__ xbf)
{
    if (blockIdx.x >= 26624) {
        int row  = (blockIdx.x - 26624) * 4 + (threadIdx.x >> 6);
        int lane = threadIdx.x & 63;
        long off = (long)row * 256 + lane * 4;
        f32x4 v4 = *(const f32x4*)(inputs + off);
        float v[4] = {v4[0], v4[1], v4[2], v4[3]};
        float s = v[0] + v[1] + v[2] + v[3];
        #pragma unroll
        for (int d = 1; d < 64; d <<= 1) s += __shfl_xor(s, d);
        float mean = s * (1.f / 256.f);
        float sq = 0.f;
        #pragma unroll
        for (int k = 0; k < 4; k++) { float dd = v[k] - mean; sq += dd * dd; }
        #pragma unroll
        for (int d = 1; d < 64; d <<= 1) sq += __shfl_xor(sq, d);
        float inv = rsqrtf(sq * (1.f / 256.f) + 1e-5f);
        short* op = xbf + off;
        #pragma unroll
        for (int k = 0; k < 4; k++)
            op[k] = f2bfs((v[k] - mean) * inv * nig[lane * 4 + k] + nib[lane * 4 + k]);
        return;
    }
    long i = (long)blockIdx.x * 256 + threadIdx.x;
    const float* s; short* d; long o;
    if      (i < 4194304) { s = Wq;  d = dWq;  o = i; }
    else if (i < 4718592) { s = Wk;  d = dWk;  o = i - 4194304; }
    else if (i < 5242880) { s = Wv;  d = dWv;  o = i - 4718592; }
    else if (i < 6029312) { s = gih; d = dgih; o = i - 5242880; }
    else                  { s = ghh; d = dghh; o = i - 6029312; }
    d[o] = f2bfs(s[o]);
}

// ---------------------------------------------------------------------------
// Prep 2: weight transposes + c1/b1g folded biases (verified r8).
// ---------------------------------------------------------------------------
__global__ __launch_bounds__(256) void transpose_b1c1_k(
    const float* __restrict__ mW1, const float* __restrict__ mW2,
    const float* __restrict__ cW1, const float* __restrict__ cW2,
    const float* __restrict__ cW3, const float* __restrict__ cW4,
    short* __restrict__ mW1T, short* __restrict__ mW2T,
    short* __restrict__ cW1T, short* __restrict__ cW2T,
    short* __restrict__ cW3T, short* __restrict__ cW4T,
    const float* __restrict__ bq, const float* __restrict__ Wk,
    const float* __restrict__ bv, const float* __restrict__ gWih,
    float* __restrict__ c1, float* __restrict__ b1g)
{
    int id = blockIdx.x, tid = threadIdx.x;
    if (id >= 1152) {
        int bid = id - 1152;
        __shared__ float red[4];
        if (bid < 256) {
            const float* row = Wk + (long)bid * 2048;
            float acc = 0.f;
            for (int d = tid; d < 2048; d += 256) acc += bq[d] * row[d];
            #pragma unroll
            for (int d = 1; d < 64; d <<= 1) acc += __shfl_xor(acc, d);
            int w = tid >> 6;
            if ((tid & 63) == 0) red[w] = acc;
            __syncthreads();
            if (tid == 0) c1[bid] = red[0] + red[1] + red[2] + red[3];
        } else {
            int t = (bid - 256) * 256 + tid;   // < 6144
            int nb = t / 384, g = t % 384;
            const float* wrow = gWih + (long)nb * 49152 + (long)g * 128;
            const float* bp = bv + nb * 128;
            float acc = 0.f;
            for (int j = 0; j < 128; j++) acc += bp[j] * wrow[j];
            b1g[t] = acc;
        }
        return;
    }
    const float* in; short* out; int R, C, tx, ty;
    if (id < 256)       { int z = id >> 4, t = id & 15; in = mW1 + z * 16384; out = mW1T + z * 16384; R = 128; C = 128; tx = t & 3;  ty = t >> 2; }
    else if (id < 512)  { id -= 256; int z = id >> 4, t = id & 15; in = mW2 + z * 16384; out = mW2T + z * 16384; R = 128; C = 128; tx = t & 3;  ty = t >> 2; }
    else if (id < 576)  { id -= 512;  in = cW1; out = cW1T; R = 128; C = 512; tx = id & 15; ty = id >> 4; }
    else if (id < 832)  { id -= 576;  in = cW2; out = cW2T; R = 512; C = 512; tx = id & 15; ty = id >> 4; }
    else if (id < 1088) { id -= 832;  in = cW3; out = cW3T; R = 512; C = 512; tx = id & 15; ty = id >> 4; }
    else                { id -= 1088; in = cW4; out = cW4T; R = 512; C = 128; tx = id & 3;  ty = id >> 2; }
    __shared__ short t[32][33];
    int c0 = tx * 32, r0 = ty * 32;
    int x = threadIdx.x & 31, y = threadIdx.x >> 5;
    #pragma unroll
    for (int k = 0; k < 32; k += 8) t[y + k][x] = f2bfs(in[(long)(r0 + y + k) * C + (c0 + x)]);
    __syncthreads();
    #pragma unroll
    for (int k = 0; k < 32; k += 8) out[(long)(c0 + y + k) * R + (r0 + x)] = t[x][y + k];
}

// ---------------------------------------------------------------------------
// Tiled MFMA GEMM core (verified; m0/n0 explicit params).
// ---------------------------------------------------------------------------
template<int OUT_MODE, int RELU, int HAS_BIAS, int A_F32, int B_F32>
DEV void gemm_core(int m0, int n0,
                   const void* __restrict__ Av, long lda, long abase,
                   const void* __restrict__ Btv, long ldb, long bbase,
                   void* __restrict__ Cv, long ldc, long cbase,
                   const float* __restrict__ bias, long biasbase, int addbias,
                   int M, int N, int K, float scale, int kbeg, int kend,
                   short* As, short* Bs)
{
    const int tid  = threadIdx.x;
    const int wave = tid >> 6, lane = tid & 63;
    const int quad = lane >> 4, l16 = lane & 15;
    const int wr = (wave >> 1) * 32, wc = (wave & 1) * 32;

    f32x4 acc[2][2] = {};

    const int lrow = tid >> 2;
    const int lk   = (tid & 3) * 8;
    const int arow = imin(m0 + lrow, M - 1);
    const int brow = imin(n0 + lrow, N - 1);
    short* asd = &As[lrow * 40 + lk];
    short* bsd = &Bs[lrow * 40 + lk];

    short8 arS = {}, brS = {};
    f32x4 arF0 = {}, arF1 = {}, brF0 = {}, brF1 = {};

    auto loadA = [&](int k0) {
        if (A_F32) {
            const float* p = (const float*)Av + abase + (long)arow * lda + lk + k0;
            arF0 = *(const f32x4*)p; arF1 = *(const f32x4*)(p + 4);
        } else {
            arS = *(const short8*)((const short*)Av + abase + (long)arow * lda + lk + k0);
        }
    };
    auto loadB = [&](int k0) {
        if (B_F32) {
            const float* p = (const float*)Btv + bbase + (long)brow * ldb + lk + k0;
            brF0 = *(const f32x4*)p; brF1 = *(const f32x4*)(p + 4);
        } else {
            brS = *(const short8*)((const short*)Btv + bbase + (long)brow * ldb + lk + k0);
        }
    };
    auto stage = [&]() {
        if (A_F32) {
            short8 t;
            #pragma unroll
            for (int j = 0; j < 4; j++) { t[j] = f2bfs(arF0[j]); t[j + 4] = f2bfs(arF1[j]); }
            *(short8*)asd = t;
        } else *(short8*)asd = arS;
        if (B_F32) {
            short8 t;
            #pragma unroll
            for (int j = 0; j < 4; j++) { t[j] = f2bfs(brF0[j]); t[j + 4] = f2bfs(brF1[j]); }
            *(short8*)bsd = t;
        } else *(short8*)bsd = brS;
    };

    loadA(kbeg); loadB(kbeg);
    for (int k0 = kbeg; k0 < kend; k0 += 32) {
        stage();
        __syncthreads();
        if (k0 + 32 < kend) { loadA(k0 + 32); loadB(k0 + 32); }
        short8 a0 = *(const short8*)&As[(wr + l16) * 40 + quad * 8];
        short8 a1 = *(const short8*)&As[(wr + 16 + l16) * 40 + quad * 8];
        short8 b0 = *(const short8*)&Bs[(wc + l16) * 40 + quad * 8];
        short8 b1 = *(const short8*)&Bs[(wc + 16 + l16) * 40 + quad * 8];
        acc[0][0] = __builtin_amdgcn_mfma_f32_16x16x32_bf16(a0, b0, acc[0][0], 0, 0, 0);
        acc[0][1] = __builtin_amdgcn_mfma_f32_16x16x32_bf16(a0, b1, acc[0][1], 0, 0, 0);
        acc[1][0] = __builtin_amdgcn_mfma_f32_16x16x32_bf16(a1, b0, acc[1][0], 0, 0, 0);
        acc[1][1] = __builtin_amdgcn_mfma_f32_16x16x32_bf16(a1, b1, acc[1][1], 0, 0, 0);
        __syncthreads();
    }

    #pragma unroll
    for (int sr = 0; sr < 2; sr++) {
        #pragma unroll
        for (int sc = 0; sc < 2; sc++) {
            int gc = n0 + wc + sc * 16 + l16;
            if (gc >= N) continue;
            float bvv = 0.f;
            if (HAS_BIAS && addbias) bvv = bias[biasbase + gc];
            #pragma unroll
            for (int r = 0; r < 4; r++) {
                int gr = m0 + wr + sr * 16 + quad * 4 + r;
                if (gr >= M) continue;
                float v = acc[sr][sc][r] * scale + bvv;
                if (RELU) v = fmaxf(v, 0.f);
                long cidx = cbase + (long)gr * ldc + gc;
                if (OUT_MODE == 0)      ((float*)Cv)[cidx] = v;
                else if (OUT_MODE == 1) ((short*)Cv)[cidx] = f2bfs(v);
                else if (OUT_MODE == 2) ((float*)Cv)[cidx] += v;
                else                    atomicAdd((float*)Cv + cidx, v);
            }
        }
    }
}

template<int OUT_MODE, int RELU, int HAS_BIAS, int A_F32, int B_F32, int SPLITK>
__global__ __launch_bounds__(256) void gemm_bt(
    const void* __restrict__ Av, long lda, long aoff,
    const void* __restrict__ Btv, long ldb, long boff,
    void* __restrict__ Cv, long ldc, long coff,
    const float* __restrict__ bias, long biasoff,
    int M, int N, int K, float scale)
{
    __shared__ __align__(16) short As[64 * 40];
    __shared__ __align__(16) short Bs[64 * 40];
    const int bz = blockIdx.z;
    long abase, bbase, cbase, biasbase;
    int kbeg, kend, addbias;
    if (SPLITK > 1) {
        int ks = K / SPLITK;
        kbeg = bz * ks; kend = kbeg + ks;
        abase = 0; bbase = 0; cbase = 0; biasbase = 0; addbias = (bz == 0);
    } else {
        kbeg = 0; kend = K;
        abase = (long)bz * aoff; bbase = (long)bz * boff; cbase = (long)bz * coff;
        biasbase = (long)bz * biasoff; addbias = 1;
    }
    gemm_core<OUT_MODE, RELU, HAS_BIAS, A_F32, B_F32>(
        blockIdx.x * 64, blockIdx.y * 64,
        Av, lda, abase, Btv, ldb, bbase, Cv, ldc, cbase,
        bias, biasbase, addbias, M, N, K, scale, kbeg, kend, As, Bs);
}

// ---------------------------------------------------------------------------
// Prep 3 (one launch): M1 (bf16 in) | WvGT (bf16 in) | concept L0 | xt.
// ---------------------------------------------------------------------------
__global__ __launch_bounds__(256) void prep3_k(
    const short* __restrict__ Wkbf, const short* __restrict__ Wqbf,
    short* __restrict__ M1bf,
    const short* __restrict__ gWihbf, const short* __restrict__ Wvbf,
    short* __restrict__ WvGTbf,
    const float* __restrict__ cvec, const short* __restrict__ cW1T,
    short* __restrict__ hA, const float* __restrict__ cb1,
    const short* __restrict__ xbf, short* __restrict__ xbfT)
{
    __shared__ __align__(16) char LDSU[10240];
    int bid = blockIdx.x;
    if (bid < 640) {
        short* As = (short*)LDSU; short* Bs = As + 2560;
        if (bid < 128) {
            gemm_core<1,0,0,0,0>((bid & 3) * 64, (bid >> 2) * 64,
                                 Wkbf, 2048, 0, Wqbf, 2048, 0, M1bf, 2048, 0,
                                 nullptr, 0, 1, 256, 2048, 2048, 1.f, 0, 2048, As, Bs);
        } else if (bid < 512) {
            int v2 = bid - 128;
            int x = v2 % 6, y = (v2 / 6) % 4, z = v2 / 24;
            gemm_core<1,0,0,0,0>(x * 64, y * 64,
                                 gWihbf, 128, (long)z * 49152, Wvbf, 2048, (long)z * 128,
                                 WvGTbf, 256, (long)z * 98304,
                                 nullptr, 0, 1, 384, 256, 128, 1.f, 0, 128, As, Bs);
        } else {
            int u = bid - 512;
            gemm_core<1,1,1,1,0>((u & 15) * 64, (u >> 4) * 64,
                                 cvec, 128, 0, cW1T, 128, 0, hA, 512, 0,
                                 cb1, 0, 1, 1024, 512, 128, 1.f, 0, 128, As, Bs);
        }
        return;
    }
    int u = bid - 640;
    int x = u & 7, y = (u >> 3) & 31, b = u >> 8;
    short (*tl)[33] = (short(*)[33])LDSU;
    int i0 = x * 32, n0 = y * 32;
    int lx = threadIdx.x & 31, ly = threadIdx.x >> 5;
    const short* ip = xbf + (long)b * 262144;
    short* op = xbfT + (long)b * 262144;
    #pragma unroll
    for (int k = 0; k < 32; k += 8) tl[ly + k][lx] = ip[(long)(n0 + ly + k) * 256 + i0 + lx];
    __syncthreads();
    #pragma unroll
    for (int k = 0; k < 32; k += 8) op[(long)(i0 + ly + k) * 1024 + n0 + lx] = tl[lx][ly + k];
}

// gi/gh now bf16: gi = up(bf16) @ WvGT + b1g (z<16); gh = slotsbf @ gWhh (z>=16).
__global__ __launch_bounds__(256) void gemm_gigh(
    const short* __restrict__ upbf, const short* __restrict__ WvGT,
    const float* __restrict__ b1g,
    const short* __restrict__ slotsbf, const short* __restrict__ gWhh,
    short* __restrict__ gibf, short* __restrict__ ghbf)
{
    __shared__ __align__(16) short As[64 * 40];
    __shared__ __align__(16) short Bs[64 * 40];
    int z = blockIdx.z;
    if (z < 16) {
        long nb = z;
        gemm_core<1, 0, 1, 0, 0>(blockIdx.x * 64, blockIdx.y * 64,
                                 upbf, 256, 0, WvGT, 256, nb * 98304,
                                 gibf, 6144, nb * 384, b1g, nb * 384, 1,
                                 256, 384, 256, 1.f, 0, 256, As, Bs);
    } else {
        long nb = z - 16;
        gemm_core<1, 0, 0, 0, 0>(blockIdx.x * 64, blockIdx.y * 64,
                                 slotsbf, 2048, nb * 128, gWhh, 128, nb * 49152,
                                 ghbf, 6144, nb * 384, nullptr, 0, 1,
                                 256, 384, 128, 1.f, 0, 128, As, Bs);
    }
}

// ---------------------------------------------------------------------------
// LN of slots over 2048 -> s_ln bf16; raw slots -> bf16; zero kqf. Block/row.
// ---------------------------------------------------------------------------
template<int INIT>
__global__ __launch_bounds__(256) void ln_slots_k(float* __restrict__ slots,
                                                  const float* __restrict__ noise,
                                                  const float* __restrict__ mu,
                                                  const float* __restrict__ ls,
                                                  const float* __restrict__ g,
                                                  const float* __restrict__ b,
                                                  short* __restrict__ s_ln,
                                                  short* __restrict__ slotsbf,
                                                  float* __restrict__ kqf)
{
    int row = blockIdx.x, tid = threadIdx.x;
    kqf[row * 256 + tid] = 0.f;  // pre-zero for split-K atomic kq GEMM
    long base = (long)row * 2048 + tid * 8;
    float v[8];
    if (INIT) {
        #pragma unroll
        for (int k = 0; k < 8; k++) {
            int d = tid * 8 + k;
            v[k] = mu[d] + expf(ls[d]) * noise[base + k];
            slots[base + k] = v[k];
        }
    } else {
        *(f32x4*)&v[0] = *(const f32x4*)(slots + base);
        *(f32x4*)&v[4] = *(const f32x4*)(slots + base + 4);
    }
    float s = 0.f;
    #pragma unroll
    for (int k = 0; k < 8; k++) s += v[k];
    #pragma unroll
    for (int d = 1; d < 64; d <<= 1) s += __shfl_xor(s, d);
    __shared__ float wsum[4], wsq[4];
    int w = tid >> 6, lane = tid & 63;
    if (lane == 0) wsum[w] = s;
    __syncthreads();
    float mean = (wsum[0] + wsum[1] + wsum[2] + wsum[3]) * (1.f / 2048.f);
    float sq = 0.f;
    #pragma unroll
    for (int k = 0; k < 8; k++) { float dd = v[k] - mean; sq += dd * dd; }
    #pragma unroll
    for (int d = 1; d < 64; d <<= 1) sq += __shfl_xor(sq, d);
    if (lane == 0) wsq[w] = sq;
    __syncthreads();
    float var = (wsq[0] + wsq[1] + wsq[2] + wsq[3]) * (1.f / 2048.f);
    float inv = rsqrtf(var + 1e-5f);
    #pragma unroll
    for (int k = 0; k < 8; k++) {
        float xn = (v[k] - mean) * inv;
        s_ln[base + k]     = f2bfs(xn * g[tid * 8 + k] + b[tid * 8 + k]);
        slotsbf[base + k] = f2bfs(v[k]);
    }
}

// ---------------------------------------------------------------------------
// FUSED softmax + up-GEMM (verified r8; up now stored bf16).
// ---------------------------------------------------------------------------
template<int WRITE_ATTN>
__global__ __launch_bounds__(256) void up2_k(const float* __restrict__ dots,
                                             const short* __restrict__ xbfT,
                                             short* __restrict__ upbf,
                                             float* __restrict__ attng)
{
    int y = blockIdx.x, b = blockIdx.y, tid = threadIdx.x;
    int w = tid >> 6, lane = tid & 63, quad = lane >> 4, l16 = lane & 15;
    __shared__ __align__(16) short attn_l[8][1032];

    #pragma unroll
    for (int sw = 0; sw < 2; sw++) {
        int s = w * 2 + sw;
        const float* dp = dots + (long)b * 8192 + s;
        float v[16];
        float mx = -1e30f;
        #pragma unroll
        for (int k = 0; k < 16; k++) { v[k] = dp[(lane + k * 64) * 8]; mx = fmaxf(mx, v[k]); }
        #pragma unroll
        for (int d = 1; d < 64; d <<= 1) mx = fmaxf(mx, __shfl_xor(mx, d));
        float sum = 0.f;
        #pragma unroll
        for (int k = 0; k < 16; k++) { v[k] = expf(v[k] - mx); sum += v[k]; }
        #pragma unroll
        for (int d = 1; d < 64; d <<= 1) sum += __shfl_xor(sum, d);
        float inv = 1.f / sum;
        float sum2 = 0.f;
        #pragma unroll
        for (int k = 0; k < 16; k++) { v[k] = v[k] * inv + 1e-8f; sum2 += v[k]; }
        #pragma unroll
        for (int d = 1; d < 64; d <<= 1) sum2 += __shfl_xor(sum2, d);
        float inv2 = 1.f / sum2;
        #pragma unroll
        for (int k = 0; k < 16; k++) {
            float a = v[k] * inv2;
            int n = lane + k * 64;
            attn_l[s][n] = f2bfs(a);
            if (WRITE_ATTN && y == 0) attng[(long)b * 8192 + n * 8 + s] = a;
        }
    }
    __syncthreads();

    int c0 = y * 64 + w * 16;
    const short* bp = xbfT + (long)b * 262144 + (long)(c0 + l16) * 1024 + quad * 8;
    f32x4 acc = {};
    for (int ks = 0; ks < 32; ks++) {
        short8 a  = *(const short8*)&attn_l[l16 & 7][ks * 32 + quad * 8];
        short8 bb = *(const short8*)(bp + ks * 32);
        acc = __builtin_amdgcn_mfma_f32_16x16x32_bf16(a, bb, acc, 0, 0, 0);
    }
    #pragma unroll
    for (int r = 0; r < 4; r++) {
        int s = quad * 4 + r;
        if (s < 8) upbf[(long)b * 2048 + s * 256 + c0 + l16] = f2bfs(acc[r]);
    }
}

// ---------------------------------------------------------------------------
// FUSED per-(nb,b) tail: GRU -> residual block-MLP (MFMA) -> BWA.
// gi/gh now bf16 inputs (bfs2f on read; biases still f32).
// ---------------------------------------------------------------------------
template<int WRITE_OUT>
__global__ __launch_bounds__(512) void resid_bwa_k(
    float* __restrict__ slots,
    const short* __restrict__ gi, const short* __restrict__ gh,
    const float* __restrict__ bih, const float* __restrict__ bhh,
    const float* __restrict__ h4,
    const short* __restrict__ mW1T, const short* __restrict__ mW2T,
    const float* __restrict__ mb1, const float* __restrict__ mb2,
    float* __restrict__ outp)
{
    int nb = blockIdx.x, b = blockIdx.y, tid = threadIdx.x;
    int lane = tid & 63, r = tid >> 6;
    int quad = lane >> 4, l16 = lane & 15;

    __shared__ __align__(16) float ml[64 * 132];
    __shared__ __align__(16) short t1b[8 * 136];
    __shared__ __align__(16) short t2b[8 * 136];
    __shared__ __align__(16) float yb[8 * 132];
    __shared__ __align__(16) float t1[8 * 128];
    __shared__ __align__(16) float sc[8 * 64];

    // Phase A: ml = BLN(h4 rows for this nb). 8 threads per proto row.
    {
        int p = tid >> 3, t8 = tid & 7;
        const float* src = h4 + (long)(p * 16 + nb) * 128 + t8 * 16;
        f32x4 a0 = *(const f32x4*)src;
        f32x4 a1 = *(const f32x4*)(src + 4);
        f32x4 a2 = *(const f32x4*)(src + 8);
        f32x4 a3 = *(const f32x4*)(src + 12);
        float s = 0.f, sq = 0.f;
        #pragma unroll
        for (int k = 0; k < 4; k++) {
            s  += a0[k] + a1[k] + a2[k] + a3[k];
            sq += a0[k]*a0[k] + a1[k]*a1[k] + a2[k]*a2[k] + a3[k]*a3[k];
        }
        #pragma unroll
        for (int d = 1; d < 8; d <<= 1) { s += __shfl_xor(s, d); sq += __shfl_xor(sq, d); }
        float mean = s * (1.f / 128.f);
        float var = sq * (1.f / 128.f) - mean * mean;
        float inv = rsqrtf(var + 1e-5f);
        float* dst = &ml[p * 132 + t8 * 16];
        #pragma unroll
        for (int k = 0; k < 4; k++) {
            dst[k]      = (a0[k] - mean) * inv;
            dst[4 + k]  = (a1[k] - mean) * inv;
            dst[8 + k]  = (a2[k] - mean) * inv;
            dst[12 + k] = (a3[k] - mean) * inv;
        }
    }

    // Phase B: GRU -> sv (regs); BLN -> t1b (bf16). r8-verified math, bf16 gi/gh.
    int row = b * 8 + r;
    long grow = (long)row * 6144 + nb * 384;
    long srow = (long)row * 2048 + nb * 128;
    int bb = nb * 384;
    float sv0, sv1;
    {
        float ir0 = bfs2f(gi[grow + lane])       + bih[bb + lane];
        float ir1 = bfs2f(gi[grow + lane + 64])  + bih[bb + lane + 64];
        float iz0 = bfs2f(gi[grow + 128 + lane]) + bih[bb + 128 + lane];
        float iz1 = bfs2f(gi[grow + 192 + lane]) + bih[bb + 192 + lane];
        float in0 = bfs2f(gi[grow + 256 + lane]) + bih[bb + 256 + lane];
        float in1 = bfs2f(gi[grow + 320 + lane]) + bih[bb + 320 + lane];
        float hr0 = bfs2f(gh[grow + lane])       + bhh[bb + lane];
        float hr1 = bfs2f(gh[grow + lane + 64])  + bhh[bb + lane + 64];
        float hz0 = bfs2f(gh[grow + 128 + lane]) + bhh[bb + 128 + lane];
        float hz1 = bfs2f(gh[grow + 192 + lane]) + bhh[bb + 192 + lane];
        float hn0 = bfs2f(gh[grow + 256 + lane]) + bhh[bb + 256 + lane];
        float hn1 = bfs2f(gh[grow + 320 + lane]) + bhh[bb + 320 + lane];
        float h0 = slots[srow + lane], h1 = slots[srow + lane + 64];
        float rg0 = sigm(ir0 + hr0), rg1 = sigm(ir1 + hr1);
        float zg0 = sigm(iz0 + hz0), zg1 = sigm(iz1 + hz1);
        sv0 = (1.f - zg0) * tanhf(in0 + rg0 * hn0) + zg0 * h0;
        sv1 = (1.f - zg1) * tanhf(in1 + rg1 * hn1) + zg1 * h1;
        float s = sv0 + sv1, sq = sv0 * sv0 + sv1 * sv1;
        #pragma unroll
        for (int d = 1; d < 64; d <<= 1) { s += __shfl_xor(s, d); sq += __shfl_xor(sq, d); }
        float mean = s * (1.f / 128.f);
        float var = sq * (1.f / 128.f) - mean * mean;
        float inv = rsqrtf(var + 1e-5f);
        t1b[r * 136 + lane]      = f2bfs((sv0 - mean) * inv);
        t1b[r * 136 + lane + 64] = f2bfs((sv1 - mean) * inv);
    }
    __syncthreads();

    // Phase C: layer1 via MFMA. wave r -> cols col..col (16-wide).
    int col = r * 16 + l16;
    {
        const short* bp = mW1T + (long)nb * 16384 + (long)col * 128 + quad * 8;
        const short* ap = &t1b[(l16 & 7) * 136 + quad * 8];
        f32x4 acc = {};
        #pragma unroll
        for (int ks = 0; ks < 4; ks++) {
            short8 a  = *(const short8*)(ap + ks * 32);
            short8 bv = *(const short8*)(bp + ks * 32);
            acc = __builtin_amdgcn_mfma_f32_16x16x32_bf16(a, bv, acc, 0, 0, 0);
        }
        float bias1 = mb1[nb * 128 + col];
        #pragma unroll
        for (int rr = 0; rr < 4; rr++) {
            int orow = quad * 4 + rr;
            if (orow < 8) t2b[orow * 136 + col] = f2bfs(fmaxf(acc[rr] + bias1, 0.f));
        }
    }
    __syncthreads();

    // Phase D: layer2 via MFMA -> yb (raw f32).
    {
        const short* bp = mW2T + (long)nb * 16384 + (long)col * 128 + quad * 8;
        const short* ap = &t2b[(l16 & 7) * 136 + quad * 8];
        f32x4 acc = {};
        #pragma unroll
        for (int ks = 0; ks < 4; ks++) {
            short8 a  = *(const short8*)(ap + ks * 32);
            short8 bv = *(const short8*)(bp + ks * 32);
            acc = __builtin_amdgcn_mfma_f32_16x16x32_bf16(a, bv, acc, 0, 0, 0);
        }
        #pragma unroll
        for (int rr = 0; rr < 4; rr++) {
            int orow = quad * 4 + rr;
            if (orow < 8) yb[orow * 132 + col] = acc[rr];
        }
    }
    __syncthreads();

    // Phase D2: residual + BLN*scale -> qn (t1). Original per-thread mapping.
    {
        float y0 = yb[r * 132 + lane]      + mb2[nb * 128 + lane]      + sv0;
        float y1 = yb[r * 132 + lane + 64] + mb2[nb * 128 + lane + 64] + sv1;
        float s = y0 + y1, sq = y0 * y0 + y1 * y1;
        #pragma unroll
        for (int d = 1; d < 64; d <<= 1) { s += __shfl_xor(s, d); sq += __shfl_xor(sq, d); }
        float mean = s * (1.f / 128.f);
        float var = sq * (1.f / 128.f) - mean * mean;
        float inv = rsqrtf(var + 1e-5f) * 0.08838834764831845f;
        t1[r * 128 + lane]      = (y0 - mean) * inv;
        t1[r * 128 + lane + 64] = (y1 - mean) * inv;
    }
    __syncthreads();

    // Phase E+F: scores + softmax (wave r handles its own slot row; p=lane)
    {
        const float* qr = &t1[r * 128];
        const float* mr = &ml[lane * 132];
        float acc0 = 0.f, acc1 = 0.f;
        #pragma unroll
        for (int j = 0; j < 128; j += 8) {
            f32x4 q0 = *(const f32x4*)(qr + j);
            f32x4 q1 = *(const f32x4*)(qr + j + 4);
            f32x4 m0 = *(const f32x4*)(mr + j);
            f32x4 m1 = *(const f32x4*)(mr + j + 4);
            acc0 += q0[0]*m0[0] + q0[1]*m0[1] + q0[2]*m0[2] + q0[3]*m0[3];
            acc1 += q1[0]*m1[0] + q1[1]*m1[1] + q1[2]*m1[2] + q1[3]*m1[3];
        }
        float acc = acc0 + acc1;
        float mx = acc;
        #pragma unroll
        for (int d = 1; d < 64; d <<= 1) mx = fmaxf(mx, __shfl_xor(mx, d));
        float e = expf(acc - mx);
        float ss = e;
        #pragma unroll
        for (int d = 1; d < 64; d <<= 1) ss += __shfl_xor(ss, d);
        sc[r * 64 + lane] = e / ss;
    }
    __syncthreads();

    // Phase G: slots = attn @ mem
    {
        const float* scr = &sc[r * 64];
        float a0 = 0.f, a1 = 0.f;
        #pragma unroll 4
        for (int p = 0; p < 64; p++) {
            float a = scr[p];
            a0 += a * ml[p * 132 + lane];
            a1 += a * ml[p * 132 + 64 + lane];
        }
        float* dst = slots + srow;
        dst[lane] = a0; dst[lane + 64] = a1;
        if (WRITE_OUT) {
            outp[srow + lane] = a0; outp[srow + lane + 64] = a1;
        }
    }
}

// ===========================================================================
extern "C" void kernel_launch(void* const* d_in, const int* in_sizes, int n_in,
                              void* d_out, int out_size, void* d_ws, size_t ws_size,
                              hipStream_t stream)
{
    (void)in_sizes; (void)n_in; (void)out_size; (void)ws_size;
    const float* inputs = (const float*)d_in[0];
    const float* noise  = (const float*)d_in[1];
    const float* smu    = (const float*)d_in[2];
    const float* sls    = (const float*)d_in[3];
    const float* Wq     = (const float*)d_in[4];
    const float* bq     = (const float*)d_in[5];
    const float* Wk     = (const float*)d_in[6];
    /* d_in[7] = bk: softmax(axis=n)-invariant; dropped */
    const float* Wv     = (const float*)d_in[8];
    const float* bv     = (const float*)d_in[9];
    const float* gWih   = (const float*)d_in[10];
    const float* gWhh   = (const float*)d_in[11];
    const float* gbih   = (const float*)d_in[12];
    const float* gbhh   = (const float*)d_in[13];
    const float* mW1    = (const float*)d_in[14];
    const float* mb1    = (const float*)d_in[15];
    const float* mW2    = (const float*)d_in[16];
    const float* mb2    = (const float*)d_in[17];
    const float* cvec   = (const float*)d_in[18];
    const float* cW1    = (const float*)d_in[19];
    const float* cb1    = (const float*)d_in[20];
    const float* cW2    = (const float*)d_in[21];
    const float* cb2    = (const float*)d_in[22];
    const float* cW3    = (const float*)d_in[23];
    const float* cb3    = (const float*)d_in[24];
    const float* cW4    = (const float*)d_in[25];
    const float* cb4    = (const float*)d_in[26];
    const float* nig    = (const float*)d_in[27];
    const float* nib    = (const float*)d_in[28];
    const float* nsg    = (const float*)d_in[29];
    const float* nsb    = (const float*)d_in[30];

    char* w = (char*)d_ws;
    auto take = [&](size_t bytes) -> char* {
        char* p = w;
        w += (bytes + 255) & ~(size_t)255;
        return p;
    };

    float* slots   = (float*)take((size_t)524288 * 4);
    short* xbf     = (short*)take((size_t)32768 * 256 * 2);
    short* xbfT    = (short*)take((size_t)32 * 256 * 1024 * 2);
    short* Wqbf    = (short*)take((size_t)2048 * 2048 * 2);
    short* Wkbf    = (short*)take((size_t)256 * 2048 * 2);
    short* Wvbf    = (short*)take((size_t)256 * 2048 * 2);
    short* gWihbf  = (short*)take((size_t)16 * 384 * 128 * 2);
    short* gWhhbf  = (short*)take((size_t)16 * 384 * 128 * 2);
    short* M1bf    = (short*)take((size_t)256 * 2048 * 2);
    short* WvGTbf  = (short*)take((size_t)16 * 384 * 256 * 2);
    float* b1g     = (float*)take((size_t)6144 * 4);
    float* c1      = (float*)take((size_t)256 * 4);
    short* mW1T    = (short*)take((size_t)16 * 128 * 128 * 2);
    short* mW2T    = (short*)take((size_t)16 * 128 * 128 * 2);
    short* cW1T    = (short*)take((size_t)512 * 128 * 2);
    short* cW2T    = (short*)take((size_t)512 * 512 * 2);
    short* cW3T    = (short*)take((size_t)512 * 512 * 2);
    short* cW4T    = (short*)take((size_t)128 * 512 * 2);
    short* hA      = (short*)take((size_t)1024 * 512 * 2);
    short* hB      = (short*)take((size_t)1024 * 512 * 2);
    float* h4      = (float*)take((size_t)1024 * 128 * 4);
    short* s_ln    = (short*)take((size_t)256 * 2048 * 2);
    short* slotsbf = (short*)take((size_t)256 * 2048 * 2);
    float* kqf     = (float*)take((size_t)256 * 256 * 4);
    float* dots    = (float*)take((size_t)32 * 1024 * 8 * 4);
    short* upbf    = (short*)take((size_t)256 * 256 * 2);
    short* gibf    = (short*)take((size_t)256 * 6144 * 2);
    short* ghbf    = (short*)take((size_t)256 * 6144 * 2);

    float* out_slots = (float*)d_out;
    float* out_attn  = (float*)d_out + 524288;

    // --- prep ---------------------------------------------------------------
    cvt_ln_k<<<28672, 256, 0, stream>>>(Wq, Wk, Wv, gWih, gWhh,
                                        Wqbf, Wkbf, Wvbf, gWihbf, gWhhbf,
                                        inputs, nig, nib, xbf);
    transpose_b1c1_k<<<1432, 256, 0, stream>>>(mW1, mW2, cW1, cW2, cW3, cW4,
                                               mW1T, mW2T, cW1T, cW2T, cW3T, cW4T,
                                               bq, Wk, bv, gWih, c1, b1g);
    prep3_k<<<8832, 256, 0, stream>>>(Wkbf, Wqbf, M1bf, gWihbf, Wvbf, WvGTbf,
                                      cvec, cW1T, hA, cb1, xbf, xbfT);

    // --- concept memory L2..L4 (L1 fused into prep3) ------------------------
    gemm_bt<1,1,1,0,0,1><<<dim3(16, 8, 1), 256, 0, stream>>>(hA, 512, 0, cW2T, 512, 0, hB, 512, 0, cb2, 0, 1024, 512, 512, 1.f);
    gemm_bt<1,1,1,0,0,1><<<dim3(16, 8, 1), 256, 0, stream>>>(hB, 512, 0, cW3T, 512, 0, hA, 512, 0, cb3, 0, 1024, 512, 512, 1.f);
    gemm_bt<0,0,1,0,0,1><<<dim3(16, 2, 1), 256, 0, stream>>>(hA, 512, 0, cW4T, 512, 0, h4, 128, 0, cb4, 0, 1024, 128, 512, 1.f);

    for (int it = 0; it < 3; ++it) {
        if (it == 0)
            ln_slots_k<1><<<256, 256, 0, stream>>>(slots, noise, smu, sls, nsg, nsb, s_ln, slotsbf, kqf);
        else
            ln_slots_k<0><<<256, 256, 0, stream>>>(slots, noise, smu, sls, nsg, nsb, s_ln, slotsbf, kqf);
        // kq[bs,i] = s_ln @ M1T^T + c1   (split-K=8, f32 atomic)
        gemm_bt<3,0,1,0,0,8><<<dim3(4, 4, 8), 256, 0, stream>>>(
            s_ln, 2048, 0, M1bf, 2048, 0, kqf, 256, 0, c1, 0, 256, 256, 2048, 1.f);
        // dots[b,n,s] = scale * x[b] @ kq[b]^T
        gemm_bt<0,0,0,0,1,1><<<dim3(16, 1, 32), 256, 0, stream>>>(
            xbf, 256, 262144, kqf, 256, 2048, dots, 8, 8192, nullptr, 0, 1024, 8, 256, QSCALE);
        // fused softmax + up-GEMM (up stored bf16)
        if (it == 2)
            up2_k<1><<<dim3(4, 32), 256, 0, stream>>>(dots, xbfT, upbf, out_attn);
        else
            up2_k<0><<<dim3(4, 32), 256, 0, stream>>>(dots, xbfT, upbf, out_attn);
        // gi and gh in one launch (bf16 in/out)
        gemm_gigh<<<dim3(4, 6, 32), 256, 0, stream>>>(upbf, WvGTbf, b1g, slotsbf, gWhhbf, gibf, ghbf);
        // fused: GRU + residual block-MLP (MFMA) + BWA (+ direct out last iter)
        if (it == 2)
            resid_bwa_k<1><<<dim3(16, 32), 512, 0, stream>>>(slots, gibf, ghbf, gbih, gbhh,
                                                             h4, mW1T, mW2T, mb1, mb2, out_slots);
        else
            resid_bwa_k<0><<<dim3(16, 32), 512, 0, stream>>>(slots, gibf, ghbf, gbih, gbhh,
                                                             h4, mW1T, mW2T, mb1, mb2, out_slots);
    }
}